// Round 1
// baseline (276.534 us; speedup 1.0000x reference)
//
#include <hip/hip_runtime.h>
#include <hip/hip_bf16.h>
#include <math.h>

typedef __attribute__((ext_vector_type(8))) short bf16x8;
typedef __attribute__((ext_vector_type(4))) float f32x4;

#define MFMA(A, B, C) __builtin_amdgcn_mfma_f32_16x16x32_bf16(A, B, C, 0, 0, 0)

__device__ __forceinline__ short f2bf(float f) {
  union { float f; unsigned u; } v;
  v.f = f;
  unsigned r = v.u + 0x7fffu + ((v.u >> 16) & 1u);
  return (short)(r >> 16);
}

// ---------------- weight transpose: Wt[n][d] bf16, n in [0,192), d in [0,1024)
// n 0..63 -> Wq col (scaled by D^-0.5 = 1/32), 64..127 -> Wk, 128..191 -> Wv
__global__ __launch_bounds__(256) void prep_w(const float* __restrict__ Wq,
                                              const float* __restrict__ Wk,
                                              const float* __restrict__ Wv,
                                              short* __restrict__ Wt) {
  int n = blockIdx.x;
  int wsel = n >> 6, col = n & 63;
  const float* W = (wsel == 0) ? Wq : ((wsel == 1) ? Wk : Wv);
  float scale = (wsel == 0) ? 0.03125f : 1.0f;
  for (int d = threadIdx.x; d < 1024; d += 256)
    Wt[n * 1024 + d] = f2bf(W[d * 64 + col] * scale);
}

// ---------------- fused QKV projection: x[16384,1024] fp32 @ Wt -> q,k (bf16
// [16384][64]) and vT (bf16 [4][64][4096]).
__global__ __launch_bounds__(256) void qkv_kernel(const float* __restrict__ x,
                                                  const short* __restrict__ Wt,
                                                  short* __restrict__ q,
                                                  short* __restrict__ k,
                                                  short* __restrict__ vT) {
  __shared__ __align__(16) short xs[64 * 32];
  const int m0 = blockIdx.x * 64;
  const int tid = threadIdx.x;
  const int wave = tid >> 6, lane = tid & 63;
  const int lr = lane & 15, lq = lane >> 4;

  const f32x4 fzero = {0.f, 0.f, 0.f, 0.f};
  f32x4 acc[12];
#pragma unroll
  for (int i = 0; i < 12; ++i) acc[i] = fzero;

  const int srow = tid >> 2, squad = tid & 3;
  const float* xg = x + (size_t)(m0 + srow) * 1024;
  // XOR swizzle on byte-offset bits 4..5 keyed by (row>>1)&3 -> 2-way max conflict
  char* xs_w = (char*)xs + srow * 64 + ((16 * squad) ^ (((srow >> 1) & 3) << 4));
  const int arow = wave * 16 + lr;
  const char* xs_r =
      (const char*)xs + arow * 64 + ((16 * lq) ^ (((arow >> 1) & 3) << 4));

  for (int k0 = 0; k0 < 1024; k0 += 32) {
    float4 a = *(const float4*)(xg + k0 + squad * 8);
    float4 b = *(const float4*)(xg + k0 + squad * 8 + 4);
    bf16x8 pk;
    pk[0] = f2bf(a.x); pk[1] = f2bf(a.y); pk[2] = f2bf(a.z); pk[3] = f2bf(a.w);
    pk[4] = f2bf(b.x); pk[5] = f2bf(b.y); pk[6] = f2bf(b.z); pk[7] = f2bf(b.w);
    __syncthreads();  // protect previous iteration's fragment reads
    *(bf16x8*)xs_w = pk;
    __syncthreads();
    bf16x8 afrag = *(const bf16x8*)xs_r;
#pragma unroll
    for (int nt = 0; nt < 12; ++nt) {
      bf16x8 bfrag = *(const bf16x8*)(Wt + (nt * 16 + lr) * 1024 + k0 + lq * 8);
      acc[nt] = MFMA(afrag, bfrag, acc[nt]);
    }
  }

#pragma unroll
  for (int nt = 0; nt < 12; ++nt) {
#pragma unroll
    for (int r = 0; r < 4; ++r) {
      int m = m0 + wave * 16 + lq * 4 + r;  // C/D: row=(lane>>4)*4+reg
      int n = nt * 16 + lr;                 //      col=lane&15
      short hval = f2bf(acc[nt][r]);
      if (nt < 4) q[m * 64 + n] = hval;
      else if (nt < 8) k[m * 64 + (n - 64)] = hval;
      else vT[((m >> 12) << 18) + ((n - 128) << 12) + (m & 4095)] = hval;
    }
  }
}

// ---------------- flash attention, causal. Grid (128 qtiles, 4 batches),
// 128 threads = 2 waves, each wave owns 16 q-rows. KVB=32.
__global__ __launch_bounds__(128) void attn_kernel(const short* __restrict__ q,
                                                   const short* __restrict__ k,
                                                   const short* __restrict__ vT,
                                                   float* __restrict__ out) {
  __shared__ __align__(16) short plds[2][16 * 32];
  const int b = blockIdx.y;
  const int qt = blockIdx.x;
  const int wave = threadIdx.x >> 6, lane = threadIdx.x & 63;
  const int lr = lane & 15, lq = lane >> 4;
  const int qw0 = qt * 32 + wave * 16;

  const short* qb = q + (((size_t)b << 12) * 64);
  const short* kb = k + (((size_t)b << 12) * 64);
  const short* vb = vT + ((size_t)b << 18);
  char* myp = (char*)plds[wave];

  // Q fragments hoisted (8 VGPR pairs); scale 1/32 already folded into Wq
  bf16x8 aq0 = *(const bf16x8*)(qb + (qw0 + lr) * 64 + lq * 8);
  bf16x8 aq1 = *(const bf16x8*)(qb + (qw0 + lr) * 64 + 32 + lq * 8);

  const f32x4 fzero = {0.f, 0.f, 0.f, 0.f};
  f32x4 o[4];
#pragma unroll
  for (int i = 0; i < 4; ++i) o[i] = fzero;
  f32x4 mrow = {-1e30f, -1e30f, -1e30f, -1e30f};
  f32x4 lrow = {0.f, 0.f, 0.f, 0.f};

  const char* prd = myp + lr * 64 + ((16 * lq) ^ (((lr >> 1) & 3) << 4));
  const int kend = qw0 + 16;  // rows qw0..qw0+15 need kv <= qw0+15

  for (int kv0 = 0; kv0 < kend; kv0 += 32) {
    // ---- S = Q K^T  (two 16-col subtiles, K=64 in two MFMA k-chunks)
    f32x4 s0 = fzero, s1 = fzero;
    {
      bf16x8 bk0 = *(const bf16x8*)(kb + (kv0 + lr) * 64 + lq * 8);
      bf16x8 bk1 = *(const bf16x8*)(kb + (kv0 + lr) * 64 + 32 + lq * 8);
      bf16x8 bk2 = *(const bf16x8*)(kb + (kv0 + 16 + lr) * 64 + lq * 8);
      bf16x8 bk3 = *(const bf16x8*)(kb + (kv0 + 16 + lr) * 64 + 32 + lq * 8);
      s0 = MFMA(aq0, bk0, s0);
      s0 = MFMA(aq1, bk1, s0);
      s1 = MFMA(aq0, bk2, s1);
      s1 = MFMA(aq1, bk3, s1);
    }

    // ---- causal mask (only the wave's final tile straddles the diagonal)
    if (kv0 + 31 > qw0) {
#pragma unroll
      for (int r = 0; r < 4; ++r) {
        int qrow = qw0 + lq * 4 + r;
        if (kv0 + lr > qrow) s0[r] = -1e30f;
        if (kv0 + 16 + lr > qrow) s1[r] = -1e30f;
      }
    }

    // ---- online softmax; row r of lane-group lq spans lanes lr=0..15 x 2 subtiles
    f32x4 rmax;
#pragma unroll
    for (int r = 0; r < 4; ++r) rmax[r] = fmaxf(s0[r], s1[r]);
#pragma unroll
    for (int off = 1; off < 16; off <<= 1)
#pragma unroll
      for (int r = 0; r < 4; ++r)
        rmax[r] = fmaxf(rmax[r], __shfl_xor(rmax[r], off));

    float p0[4], p1[4];
    f32x4 psum;
#pragma unroll
    for (int r = 0; r < 4; ++r) {
      float mn = fmaxf(mrow[r], rmax[r]);
      float sc = exp2f((mrow[r] - mn) * 1.44269504f);
      p0[r] = exp2f((s0[r] - mn) * 1.44269504f);
      p1[r] = exp2f((s1[r] - mn) * 1.44269504f);
      psum[r] = p0[r] + p1[r];
      mrow[r] = mn;
      lrow[r] *= sc;
#pragma unroll
      for (int ht = 0; ht < 4; ++ht) o[ht][r] *= sc;
    }
#pragma unroll
    for (int off = 1; off < 16; off <<= 1)
#pragma unroll
      for (int r = 0; r < 4; ++r) psum[r] += __shfl_xor(psum[r], off);
#pragma unroll
    for (int r = 0; r < 4; ++r) lrow[r] += psum[r];

    // ---- P -> bf16 -> per-wave swizzled LDS (C-layout -> A-layout transpose)
#pragma unroll
    for (int r = 0; r < 4; ++r) {
      int prow = lq * 4 + r;
      int swz = ((prow >> 1) & 3) << 4;
      *(short*)(myp + prow * 64 + ((2 * lr) ^ swz)) = f2bf(p0[r]);
      *(short*)(myp + prow * 64 + ((2 * (16 + lr)) ^ swz)) = f2bf(p1[r]);
    }
    bf16x8 ap = *(const bf16x8*)prd;  // A-frag: row=lr, s=lq*8..+8

    // ---- O += P V ; vT gives contiguous B-fragments
#pragma unroll
    for (int ht = 0; ht < 4; ++ht) {
      bf16x8 bv = *(const bf16x8*)(vb + (ht * 16 + lr) * 4096 + kv0 + lq * 8);
      o[ht] = MFMA(ap, bv, o[ht]);
    }
  }

#pragma unroll
  for (int r = 0; r < 4; ++r) {
    float inv = 1.0f / lrow[r];
    int m = (b << 12) + qw0 + lq * 4 + r;
#pragma unroll
    for (int ht = 0; ht < 4; ++ht)
      out[m * 64 + ht * 16 + lr] = o[ht][r] * inv;
  }
}

extern "C" void kernel_launch(void* const* d_in, const int* in_sizes, int n_in,
                              void* d_out, int out_size, void* d_ws, size_t ws_size,
                              hipStream_t stream) {
  const float* x = (const float*)d_in[0];
  const float* Wq = (const float*)d_in[1];
  const float* Wk = (const float*)d_in[2];
  const float* Wv = (const float*)d_in[3];
  float* out = (float*)d_out;

  char* w = (char*)d_ws;
  short* qb = (short*)(w);                                // 2 MiB
  short* kb = (short*)(w + (size_t)2 * 1024 * 1024);      // 2 MiB
  short* vT = (short*)(w + (size_t)4 * 1024 * 1024);      // 2 MiB
  short* Wt = (short*)(w + (size_t)6 * 1024 * 1024);      // 384 KiB

  prep_w<<<192, 256, 0, stream>>>(Wq, Wk, Wv, Wt);
  qkv_kernel<<<256, 256, 0, stream>>>(x, Wt, qb, kb, vT);
  attn_kernel<<<dim3(128, 4), 128, 0, stream>>>(qb, kb, vT, out);
}

// Round 2
// 207.820 us; speedup vs baseline: 1.3306x; 1.3306x over previous
//
#include <hip/hip_runtime.h>
#include <hip/hip_bf16.h>
#include <math.h>

typedef __attribute__((ext_vector_type(8))) short bf16x8;
typedef __attribute__((ext_vector_type(4))) float f32x4;

#define MFMA(A, B, C) __builtin_amdgcn_mfma_f32_16x16x32_bf16(A, B, C, 0, 0, 0)
#define LOG2E 1.44269504f

__device__ __forceinline__ short f2bf(float f) {
  union { float f; unsigned u; } v;
  v.f = f;
  unsigned r = v.u + 0x7fffu + ((v.u >> 16) & 1u);
  return (short)(r >> 16);
}

// ---------------- weight transpose: Wt[n][d] bf16, n in [0,192), d in [0,1024)
// n 0..63 -> Wq col (scaled by D^-0.5 = 1/32), 64..127 -> Wk, 128..191 -> Wv
__global__ __launch_bounds__(256) void prep_w(const float* __restrict__ Wq,
                                              const float* __restrict__ Wk,
                                              const float* __restrict__ Wv,
                                              short* __restrict__ Wt) {
  int n = blockIdx.x;
  int wsel = n >> 6, col = n & 63;
  const float* W = (wsel == 0) ? Wq : ((wsel == 1) ? Wk : Wv);
  float scale = (wsel == 0) ? 0.03125f : 1.0f;
  for (int d = threadIdx.x; d < 1024; d += 256)
    Wt[n * 1024 + d] = f2bf(W[d * 64 + col] * scale);
}

// ---------------- fused QKV projection, barrier-free: A-fragments straight
// from global (lane lr owns row m0+w*16+lr, reads its k-slice), depth-1
// register pipeline. Outputs q,k [16384][64] bf16 and vT [4][64][4096] bf16.
__global__ __launch_bounds__(256) void qkv_kernel(const float* __restrict__ x,
                                                  const short* __restrict__ Wt,
                                                  short* __restrict__ q,
                                                  short* __restrict__ k,
                                                  short* __restrict__ vT) {
  const int m0 = blockIdx.x * 64;
  const int tid = threadIdx.x;
  const int wave = tid >> 6, lane = tid & 63;
  const int lr = lane & 15, lq = lane >> 4;

  const f32x4 fzero = {0.f, 0.f, 0.f, 0.f};
  f32x4 acc[12];
#pragma unroll
  for (int i = 0; i < 12; ++i) acc[i] = fzero;

  const float* xg = x + (size_t)(m0 + wave * 16 + lr) * 1024 + lq * 8;

  float4 a0 = *(const float4*)(xg);
  float4 a1 = *(const float4*)(xg + 4);

#pragma unroll 4
  for (int k0 = 0; k0 < 1024; k0 += 32) {
    float4 n0 = a0, n1 = a1;
    if (k0 + 32 < 1024) {
      n0 = *(const float4*)(xg + k0 + 32);
      n1 = *(const float4*)(xg + k0 + 36);
    }
    bf16x8 af;
    af[0] = f2bf(a0.x); af[1] = f2bf(a0.y); af[2] = f2bf(a0.z); af[3] = f2bf(a0.w);
    af[4] = f2bf(a1.x); af[5] = f2bf(a1.y); af[6] = f2bf(a1.z); af[7] = f2bf(a1.w);
#pragma unroll
    for (int nt = 0; nt < 12; ++nt) {
      bf16x8 bfrag = *(const bf16x8*)(Wt + (nt * 16 + lr) * 1024 + k0 + lq * 8);
      acc[nt] = MFMA(af, bfrag, acc[nt]);
    }
    a0 = n0; a1 = n1;
  }

#pragma unroll
  for (int nt = 0; nt < 12; ++nt) {
#pragma unroll
    for (int r = 0; r < 4; ++r) {
      int m = m0 + wave * 16 + lq * 4 + r;  // C/D: row=(lane>>4)*4+reg
      int n = nt * 16 + lr;                 //      col=lane&15
      short hval = f2bf(acc[nt][r]);
      if (nt < 4) q[m * 64 + n] = hval;
      else if (nt < 8) k[m * 64 + (n - 64)] = hval;
      else vT[((m >> 12) << 18) + ((n - 128) << 12) + (m & 4095)] = hval;
    }
  }
}

// ---------------- split-K causal flash, partial pass.
// Work units: (batch b, 16-row q-group g, 1024-wide KV segment s), enumerated
// exactly (no empty units): per batch 640 units. 2560 blocks x 1 wave.
// XCD-aware: id&7 selects XCD (dispatch round-robin); 2 XCDs per batch so
// each XCD's L2 holds one batch's 1MB K/V working set.
__global__ __launch_bounds__(64) void attn_partial(const short* __restrict__ q,
                                                   const short* __restrict__ k,
                                                   const short* __restrict__ vT,
                                                   float* __restrict__ Op,
                                                   float* __restrict__ mp,
                                                   float* __restrict__ lp) {
  __shared__ __align__(16) short plds[16 * 64];
  const int id = blockIdx.x;
  const int xcd = id & 7;
  const int b = xcd >> 1;
  const int u = ((id >> 3) << 1) | (xcd & 1);  // 0..639
  int g, s;
  if (u < 64) { g = u; s = 0; }
  else if (u < 192) { int t = u - 64; g = 64 + (t >> 1); s = t & 1; }
  else if (u < 384) { int t = u - 192; int q3 = t / 3; g = 128 + q3; s = t - q3 * 3; }
  else { int t = u - 384; g = 192 + (t >> 2); s = t & 3; }
  const int nseg = (g >> 6) + 1;
  const int qr0 = g << 4;
  const int kv_lo = s << 10;
  const int kv_hi = (s == nseg - 1) ? (qr0 + 16) : ((s + 1) << 10);

  const int lane = threadIdx.x & 63;
  const int lr = lane & 15, lq = lane >> 4;

  const short* qb = q + ((size_t)b << 12) * 64;
  const short* kb = k + ((size_t)b << 12) * 64;
  const short* vb = vT + ((size_t)b << 18);

  bf16x8 aq0 = *(const bf16x8*)(qb + (qr0 + lr) * 64 + lq * 8);
  bf16x8 aq1 = *(const bf16x8*)(qb + (qr0 + lr) * 64 + 32 + lq * 8);

  const f32x4 fzero = {0.f, 0.f, 0.f, 0.f};
  f32x4 o[4];
#pragma unroll
  for (int i = 0; i < 4; ++i) o[i] = fzero;
  f32x4 mrow = {-1e30f, -1e30f, -1e30f, -1e30f};
  f32x4 lrow = {0.f, 0.f, 0.f, 0.f};

  char* pw = (char*)plds;
  // P LDS: row*128 bytes, XOR swizzle byte^=(row&7)<<4 -> conflict-free b128 read
  const char* pr0 = (char*)plds + lr * 128 + ((16 * lq) ^ ((lr & 7) << 4));
  const char* pr1 = (char*)plds + lr * 128 + ((64 + 16 * lq) ^ ((lr & 7) << 4));

  for (int kv0 = kv_lo; kv0 < kv_hi; kv0 += 64) {
    bf16x8 bk[8], bv[8];
#pragma unroll
    for (int t = 0; t < 4; ++t) {
      bk[2 * t]     = *(const bf16x8*)(kb + (kv0 + t * 16 + lr) * 64 + lq * 8);
      bk[2 * t + 1] = *(const bf16x8*)(kb + (kv0 + t * 16 + lr) * 64 + 32 + lq * 8);
    }
#pragma unroll
    for (int ht = 0; ht < 4; ++ht) {  // V prefetch: independent of softmax
      bv[2 * ht]     = *(const bf16x8*)(vb + (ht * 16 + lr) * 4096 + kv0 + lq * 8);
      bv[2 * ht + 1] = *(const bf16x8*)(vb + (ht * 16 + lr) * 4096 + kv0 + 32 + lq * 8);
    }

    f32x4 sv[4];
#pragma unroll
    for (int t = 0; t < 4; ++t) {
      sv[t] = MFMA(aq0, bk[2 * t], fzero);
      sv[t] = MFMA(aq1, bk[2 * t + 1], sv[t]);
    }

    if (kv0 + 63 > qr0) {  // only diagonal tiles
#pragma unroll
      for (int t = 0; t < 4; ++t)
#pragma unroll
        for (int r = 0; r < 4; ++r)
          if (kv0 + t * 16 + lr > qr0 + lq * 4 + r) sv[t][r] = -1e30f;
    }

    f32x4 rmax;
#pragma unroll
    for (int r = 0; r < 4; ++r)
      rmax[r] = fmaxf(fmaxf(sv[0][r], sv[1][r]), fmaxf(sv[2][r], sv[3][r]));
#pragma unroll
    for (int off = 1; off < 16; off <<= 1)
#pragma unroll
      for (int r = 0; r < 4; ++r)
        rmax[r] = fmaxf(rmax[r], __shfl_xor(rmax[r], off));

    f32x4 psum;
#pragma unroll
    for (int r = 0; r < 4; ++r) {
      float mn = fmaxf(mrow[r], rmax[r]);
      float sc = exp2f((mrow[r] - mn) * LOG2E);
      mrow[r] = mn;
      lrow[r] *= sc;
#pragma unroll
      for (int ht = 0; ht < 4; ++ht) o[ht][r] *= sc;
      int row = lq * 4 + r;
      int swz = (row & 7) << 4;
      char* rowp = pw + row * 128;
      float ps = 0.f;
#pragma unroll
      for (int t = 0; t < 4; ++t) {
        float pv = exp2f((sv[t][r] - mn) * LOG2E);
        ps += pv;
        *(short*)(rowp + ((2 * (16 * t + lr)) ^ swz)) = f2bf(pv);
      }
      psum[r] = ps;
    }
#pragma unroll
    for (int off = 1; off < 16; off <<= 1)
#pragma unroll
      for (int r = 0; r < 4; ++r) psum[r] += __shfl_xor(psum[r], off);
#pragma unroll
    for (int r = 0; r < 4; ++r) lrow[r] += psum[r];

    bf16x8 ap0 = *(const bf16x8*)pr0;  // A-frag of P: row=lr, kv=lq*8 (+32)
    bf16x8 ap1 = *(const bf16x8*)pr1;
#pragma unroll
    for (int ht = 0; ht < 4; ++ht) {
      o[ht] = MFMA(ap0, bv[2 * ht], o[ht]);
      o[ht] = MFMA(ap1, bv[2 * ht + 1], o[ht]);
    }
  }

  const int pid = b * 640 + u;
  float* Ob = Op + (size_t)pid * 1024;
#pragma unroll
  for (int ht = 0; ht < 4; ++ht)
#pragma unroll
    for (int r = 0; r < 4; ++r)
      Ob[(lq * 4 + r) * 64 + ht * 16 + lr] = o[ht][r];
  if (lr == 0) {
#pragma unroll
    for (int r = 0; r < 4; ++r) {
      mp[pid * 16 + lq * 4 + r] = mrow[r];
      lp[pid * 16 + lq * 4 + r] = lrow[r];
    }
  }
}

// ---------------- combine <=4 segment partials per (b, g), normalize, write out
__global__ __launch_bounds__(64) void attn_combine(const float* __restrict__ Op,
                                                   const float* __restrict__ mp,
                                                   const float* __restrict__ lp,
                                                   float* __restrict__ out) {
  const int g = blockIdx.x;  // 0..255
  const int b = blockIdx.y;  // 0..3
  const int nseg = (g >> 6) + 1;
  int segbase;
  if (g < 64) segbase = g;
  else if (g < 128) segbase = 64 + (g - 64) * 2;
  else if (g < 192) segbase = 192 + (g - 128) * 3;
  else segbase = 384 + (g - 192) * 4;
  const int base = b * 640 + segbase;
  const int col = threadIdx.x;  // 0..63

  for (int row = 0; row < 16; ++row) {
    float mm = -1e30f;
    for (int s = 0; s < nseg; ++s)
      mm = fmaxf(mm, mp[(base + s) * 16 + row]);
    float lsum = 0.f, osum = 0.f;
    for (int s = 0; s < nseg; ++s) {
      float wgt = exp2f((mp[(base + s) * 16 + row] - mm) * LOG2E);
      lsum += lp[(base + s) * 16 + row] * wgt;
      osum += Op[(size_t)(base + s) * 1024 + row * 64 + col] * wgt;
    }
    out[((size_t)b * 4096 + g * 16 + row) * 64 + col] = osum / lsum;
  }
}

extern "C" void kernel_launch(void* const* d_in, const int* in_sizes, int n_in,
                              void* d_out, int out_size, void* d_ws, size_t ws_size,
                              hipStream_t stream) {
  const float* x = (const float*)d_in[0];
  const float* Wq = (const float*)d_in[1];
  const float* Wk = (const float*)d_in[2];
  const float* Wv = (const float*)d_in[3];
  float* out = (float*)d_out;

  char* w = (char*)d_ws;
  short* qb = (short*)(w);                                 // 2 MiB
  short* kb = (short*)(w + (size_t)2 * 1024 * 1024);       // 2 MiB
  short* vT = (short*)(w + (size_t)4 * 1024 * 1024);       // 2 MiB
  short* Wt = (short*)(w + (size_t)6 * 1024 * 1024);       // 384 KiB
  float* mp = (float*)(w + (size_t)7 * 1024 * 1024);       // 160 KiB
  float* lp = (float*)(w + (size_t)7 * 1024 * 1024 + 256 * 1024);  // 160 KiB
  float* Op = (float*)(w + (size_t)8 * 1024 * 1024);       // 10 MiB

  prep_w<<<192, 256, 0, stream>>>(Wq, Wk, Wv, Wt);
  qkv_kernel<<<256, 256, 0, stream>>>(x, Wt, qb, kb, vT);
  attn_partial<<<2560, 64, 0, stream>>>(qb, kb, vT, Op, mp, lp);
  attn_combine<<<dim3(256, 4), 64, 0, stream>>>(Op, mp, lp, out);
}

// Round 3
// 149.286 us; speedup vs baseline: 1.8524x; 1.3921x over previous
//
#include <hip/hip_runtime.h>
#include <hip/hip_bf16.h>
#include <math.h>

typedef __attribute__((ext_vector_type(8))) short bf16x8;
typedef __attribute__((ext_vector_type(4))) float f32x4;

#define MFMA(A, B, C) __builtin_amdgcn_mfma_f32_16x16x32_bf16(A, B, C, 0, 0, 0)
#define LOG2E 1.44269504f

__device__ __forceinline__ short f2bf(float f) {
  union { __hip_bfloat16 b; short s; } v;
  v.b = __float2bfloat16(f);  // RTN, HW cvt
  return v.s;
}

__device__ __forceinline__ bf16x8 cvt8(float4 a, float4 b) {
  bf16x8 r;
  r[0] = f2bf(a.x); r[1] = f2bf(a.y); r[2] = f2bf(a.z); r[3] = f2bf(a.w);
  r[4] = f2bf(b.x); r[5] = f2bf(b.y); r[6] = f2bf(b.z); r[7] = f2bf(b.w);
  return r;
}

// ---------------- weight transpose via LDS tiles: Wt[n][d] bf16, n in [0,192)
// n 0..63 -> Wq col (x 1/32 score scale), 64..127 -> Wk, 128..191 -> Wv
__global__ __launch_bounds__(256) void prep_w(const float* __restrict__ Wq,
                                              const float* __restrict__ Wk,
                                              const float* __restrict__ Wv,
                                              short* __restrict__ Wt) {
  __shared__ float ls[64][65];
  const int wsel = blockIdx.x >> 4;   // 0..2
  const int dt = blockIdx.x & 15;     // d-tile
  const float* W = (wsel == 0) ? Wq : ((wsel == 1) ? Wk : Wv);
  const float scale = (wsel == 0) ? 0.03125f : 1.0f;
  const int d0 = dt * 64;
  const int rr = threadIdx.x >> 4;    // 0..15
  const int cc = threadIdx.x & 15;    // 0..15
#pragma unroll
  for (int p = 0; p < 4; ++p) {       // coalesced 256B row reads
    int d = rr + p * 16;
    float4 v = *(const float4*)(W + (size_t)(d0 + d) * 64 + cc * 4);
    ls[d][cc * 4 + 0] = v.x; ls[d][cc * 4 + 1] = v.y;
    ls[d][cc * 4 + 2] = v.z; ls[d][cc * 4 + 3] = v.w;
  }
  __syncthreads();
#pragma unroll
  for (int p = 0; p < 4; ++p) {       // transposed read, coalesced 8B writes
    int h = rr + p * 16;
    short4 o;
    o.x = f2bf(ls[cc * 4 + 0][h] * scale);
    o.y = f2bf(ls[cc * 4 + 1][h] * scale);
    o.z = f2bf(ls[cc * 4 + 2][h] * scale);
    o.w = f2bf(ls[cc * 4 + 3][h] * scale);
    *(short4*)(Wt + (size_t)(wsel * 64 + h) * 1024 + d0 + cc * 4) = o;
  }
}

// ---------------- fused QKV projection, barrier-free, 2-stage reg pipeline.
// Grid 512 blocks x 256 thr; block owns 32 rows; wave w computes nt w*3..w*3+2
// (N-split 4) -> 2048 waves (8/CU). Outputs q,k [16384][64], vT [4][64][4096].
__global__ __launch_bounds__(256) void qkv_kernel(const float* __restrict__ x,
                                                  const short* __restrict__ Wt,
                                                  short* __restrict__ q,
                                                  short* __restrict__ k,
                                                  short* __restrict__ vT) {
  const int m0 = blockIdx.x * 32;
  const int wave = threadIdx.x >> 6, lane = threadIdx.x & 63;
  const int lr = lane & 15, lq = lane >> 4;

  const f32x4 fzero = {0.f, 0.f, 0.f, 0.f};
  f32x4 acc[6];  // [rowfrag 2][nt 3]
#pragma unroll
  for (int i = 0; i < 6; ++i) acc[i] = fzero;

  const float* xr0 = x + (size_t)(m0 + lr) * 1024 + lq * 8;
  const float* xr1 = x + (size_t)(m0 + 16 + lr) * 1024 + lq * 8;
  const short* wb = Wt + (size_t)(wave * 3 * 16 + lr) * 1024 + lq * 8;

#define LOADX(X0, X1, X2, X3, kk)              \
  X0 = *(const float4*)(xr0 + (kk));           \
  X1 = *(const float4*)(xr0 + (kk) + 4);       \
  X2 = *(const float4*)(xr1 + (kk));           \
  X3 = *(const float4*)(xr1 + (kk) + 4);
#define LOADW(B0, B1, B2, kk)                  \
  B0 = *(const bf16x8*)(wb + (kk));            \
  B1 = *(const bf16x8*)(wb + 16 * 1024 + (kk));\
  B2 = *(const bf16x8*)(wb + 32 * 1024 + (kk));

  float4 ax0, ax1, ax2, ax3, bx0, bx1, bx2, bx3;
  bf16x8 aw0, aw1, aw2, bw0, bw1, bw2;
  LOADX(ax0, ax1, ax2, ax3, 0) LOADW(aw0, aw1, aw2, 0)
  LOADX(bx0, bx1, bx2, bx3, 32) LOADW(bw0, bw1, bw2, 32)

  for (int k0 = 0; k0 < 1024; k0 += 64) {
    {  // stage A: compute step k0; issue loads for k0+64 before MFMAs
      bf16x8 af0 = cvt8(ax0, ax1), af1 = cvt8(ax2, ax3);
      bf16x8 u0 = aw0, u1 = aw1, u2 = aw2;
      if (k0 + 64 < 1024) {
        LOADX(ax0, ax1, ax2, ax3, k0 + 64) LOADW(aw0, aw1, aw2, k0 + 64)
      }
      acc[0] = MFMA(af0, u0, acc[0]);
      acc[1] = MFMA(af0, u1, acc[1]);
      acc[2] = MFMA(af0, u2, acc[2]);
      acc[3] = MFMA(af1, u0, acc[3]);
      acc[4] = MFMA(af1, u1, acc[4]);
      acc[5] = MFMA(af1, u2, acc[5]);
    }
    {  // stage B: compute step k0+32; issue loads for k0+96
      bf16x8 af0 = cvt8(bx0, bx1), af1 = cvt8(bx2, bx3);
      bf16x8 u0 = bw0, u1 = bw1, u2 = bw2;
      if (k0 + 96 < 1024) {
        LOADX(bx0, bx1, bx2, bx3, k0 + 96) LOADW(bw0, bw1, bw2, k0 + 96)
      }
      acc[0] = MFMA(af0, u0, acc[0]);
      acc[1] = MFMA(af0, u1, acc[1]);
      acc[2] = MFMA(af0, u2, acc[2]);
      acc[3] = MFMA(af1, u0, acc[3]);
      acc[4] = MFMA(af1, u1, acc[4]);
      acc[5] = MFMA(af1, u2, acc[5]);
    }
  }
#undef LOADX
#undef LOADW

#pragma unroll
  for (int rf = 0; rf < 2; ++rf) {
#pragma unroll
    for (int j = 0; j < 3; ++j) {
      int nt = wave * 3 + j;
#pragma unroll
      for (int r = 0; r < 4; ++r) {
        int m = m0 + rf * 16 + lq * 4 + r;  // C/D: row=(lane>>4)*4+reg
        int n = nt * 16 + lr;               //      col=lane&15
        short hval = f2bf(acc[rf * 3 + j][r]);
        if (nt < 4) q[m * 64 + n] = hval;
        else if (nt < 8) k[m * 64 + (n - 64)] = hval;
        else vT[((m >> 12) << 18) + ((n - 128) << 12) + (m & 4095)] = hval;
      }
    }
  }
}

// ---------------- split-K causal flash, partial pass (unchanged from r2).
// Units: (b, 16-row q-group g, 1024-wide KV segment s); 640/batch, 2560 blocks.
__global__ __launch_bounds__(64) void attn_partial(const short* __restrict__ q,
                                                   const short* __restrict__ k,
                                                   const short* __restrict__ vT,
                                                   float* __restrict__ Op,
                                                   float* __restrict__ mp,
                                                   float* __restrict__ lp) {
  __shared__ __align__(16) short plds[16 * 64];
  const int id = blockIdx.x;
  const int xcd = id & 7;
  const int b = xcd >> 1;
  const int u = ((id >> 3) << 1) | (xcd & 1);  // 0..639
  int g, s;
  if (u < 64) { g = u; s = 0; }
  else if (u < 192) { int t = u - 64; g = 64 + (t >> 1); s = t & 1; }
  else if (u < 384) { int t = u - 192; int q3 = t / 3; g = 128 + q3; s = t - q3 * 3; }
  else { int t = u - 384; g = 192 + (t >> 2); s = t & 3; }
  const int nseg = (g >> 6) + 1;
  const int qr0 = g << 4;
  const int kv_lo = s << 10;
  const int kv_hi = (s == nseg - 1) ? (qr0 + 16) : ((s + 1) << 10);

  const int lane = threadIdx.x & 63;
  const int lr = lane & 15, lq = lane >> 4;

  const short* qb = q + ((size_t)b << 12) * 64;
  const short* kb = k + ((size_t)b << 12) * 64;
  const short* vb = vT + ((size_t)b << 18);

  bf16x8 aq0 = *(const bf16x8*)(qb + (qr0 + lr) * 64 + lq * 8);
  bf16x8 aq1 = *(const bf16x8*)(qb + (qr0 + lr) * 64 + 32 + lq * 8);

  const f32x4 fzero = {0.f, 0.f, 0.f, 0.f};
  f32x4 o[4];
#pragma unroll
  for (int i = 0; i < 4; ++i) o[i] = fzero;
  f32x4 mrow = {-1e30f, -1e30f, -1e30f, -1e30f};
  f32x4 lrow = {0.f, 0.f, 0.f, 0.f};

  char* pw = (char*)plds;
  const char* pr0 = (char*)plds + lr * 128 + ((16 * lq) ^ ((lr & 7) << 4));
  const char* pr1 = (char*)plds + lr * 128 + ((64 + 16 * lq) ^ ((lr & 7) << 4));

  for (int kv0 = kv_lo; kv0 < kv_hi; kv0 += 64) {
    bf16x8 bk[8], bv[8];
#pragma unroll
    for (int t = 0; t < 4; ++t) {
      bk[2 * t]     = *(const bf16x8*)(kb + (kv0 + t * 16 + lr) * 64 + lq * 8);
      bk[2 * t + 1] = *(const bf16x8*)(kb + (kv0 + t * 16 + lr) * 64 + 32 + lq * 8);
    }
#pragma unroll
    for (int ht = 0; ht < 4; ++ht) {
      bv[2 * ht]     = *(const bf16x8*)(vb + (ht * 16 + lr) * 4096 + kv0 + lq * 8);
      bv[2 * ht + 1] = *(const bf16x8*)(vb + (ht * 16 + lr) * 4096 + kv0 + 32 + lq * 8);
    }

    f32x4 sv[4];
#pragma unroll
    for (int t = 0; t < 4; ++t) {
      sv[t] = MFMA(aq0, bk[2 * t], fzero);
      sv[t] = MFMA(aq1, bk[2 * t + 1], sv[t]);
    }

    if (kv0 + 63 > qr0) {
#pragma unroll
      for (int t = 0; t < 4; ++t)
#pragma unroll
        for (int r = 0; r < 4; ++r)
          if (kv0 + t * 16 + lr > qr0 + lq * 4 + r) sv[t][r] = -1e30f;
    }

    f32x4 rmax;
#pragma unroll
    for (int r = 0; r < 4; ++r)
      rmax[r] = fmaxf(fmaxf(sv[0][r], sv[1][r]), fmaxf(sv[2][r], sv[3][r]));
#pragma unroll
    for (int off = 1; off < 16; off <<= 1)
#pragma unroll
      for (int r = 0; r < 4; ++r)
        rmax[r] = fmaxf(rmax[r], __shfl_xor(rmax[r], off));

    f32x4 psum;
#pragma unroll
    for (int r = 0; r < 4; ++r) {
      float mn = fmaxf(mrow[r], rmax[r]);
      float sc = exp2f((mrow[r] - mn) * LOG2E);
      mrow[r] = mn;
      lrow[r] *= sc;
#pragma unroll
      for (int ht = 0; ht < 4; ++ht) o[ht][r] *= sc;
      int row = lq * 4 + r;
      int swz = (row & 7) << 4;
      char* rowp = pw + row * 128;
      float ps = 0.f;
#pragma unroll
      for (int t = 0; t < 4; ++t) {
        float pv = exp2f((sv[t][r] - mn) * LOG2E);
        ps += pv;
        *(short*)(rowp + ((2 * (16 * t + lr)) ^ swz)) = f2bf(pv);
      }
      psum[r] = ps;
    }
#pragma unroll
    for (int off = 1; off < 16; off <<= 1)
#pragma unroll
      for (int r = 0; r < 4; ++r) psum[r] += __shfl_xor(psum[r], off);
#pragma unroll
    for (int r = 0; r < 4; ++r) lrow[r] += psum[r];

    bf16x8 ap0 = *(const bf16x8*)pr0;
    bf16x8 ap1 = *(const bf16x8*)pr1;
#pragma unroll
    for (int ht = 0; ht < 4; ++ht) {
      o[ht] = MFMA(ap0, bv[2 * ht], o[ht]);
      o[ht] = MFMA(ap1, bv[2 * ht + 1], o[ht]);
    }
  }

  const int pid = b * 640 + u;
  float* Ob = Op + (size_t)pid * 1024;
#pragma unroll
  for (int ht = 0; ht < 4; ++ht)
#pragma unroll
    for (int r = 0; r < 4; ++r)
      Ob[(lq * 4 + r) * 64 + ht * 16 + lr] = o[ht][r];
  if (lr == 0) {
#pragma unroll
    for (int r = 0; r < 4; ++r) {
      mp[pid * 16 + lq * 4 + r] = mrow[r];
      lp[pid * 16 + lq * 4 + r] = lrow[r];
    }
  }
}

// ---------------- combine <=4 segment partials per (b,g); 256 thr, 4 rows each
__global__ __launch_bounds__(256) void attn_combine(const float* __restrict__ Op,
                                                    const float* __restrict__ mp,
                                                    const float* __restrict__ lp,
                                                    float* __restrict__ out) {
  const int g = blockIdx.x;  // 0..255
  const int b = blockIdx.y;  // 0..3
  const int nseg = (g >> 6) + 1;
  int segbase;
  if (g < 64) segbase = g;
  else if (g < 128) segbase = 64 + (g - 64) * 2;
  else if (g < 192) segbase = 192 + (g - 128) * 3;
  else segbase = 384 + (g - 192) * 4;
  const int base = b * 640 + segbase;
  const int col = threadIdx.x & 63;
  const int rq = threadIdx.x >> 6;  // 4 rows per thread

#pragma unroll
  for (int rr = 0; rr < 4; ++rr) {
    int row = rq * 4 + rr;
    float mv[4], lv[4], ov[4];
#pragma unroll 4
    for (int s = 0; s < nseg; ++s) {
      mv[s] = mp[(base + s) * 16 + row];
      lv[s] = lp[(base + s) * 16 + row];
      ov[s] = Op[(size_t)(base + s) * 1024 + row * 64 + col];
    }
    float mm = -1e30f;
#pragma unroll 4
    for (int s = 0; s < nseg; ++s) mm = fmaxf(mm, mv[s]);
    float lsum = 0.f, osum = 0.f;
#pragma unroll 4
    for (int s = 0; s < nseg; ++s) {
      float wgt = exp2f((mv[s] - mm) * LOG2E);
      lsum += lv[s] * wgt;
      osum += ov[s] * wgt;
    }
    out[((size_t)b * 4096 + g * 16 + row) * 64 + col] = osum / lsum;
  }
}

extern "C" void kernel_launch(void* const* d_in, const int* in_sizes, int n_in,
                              void* d_out, int out_size, void* d_ws, size_t ws_size,
                              hipStream_t stream) {
  const float* x = (const float*)d_in[0];
  const float* Wq = (const float*)d_in[1];
  const float* Wk = (const float*)d_in[2];
  const float* Wv = (const float*)d_in[3];
  float* out = (float*)d_out;

  char* w = (char*)d_ws;
  short* qb = (short*)(w);                                 // 2 MiB
  short* kb = (short*)(w + (size_t)2 * 1024 * 1024);       // 2 MiB
  short* vT = (short*)(w + (size_t)4 * 1024 * 1024);       // 2 MiB
  short* Wt = (short*)(w + (size_t)6 * 1024 * 1024);       // 384 KiB
  float* mp = (float*)(w + (size_t)7 * 1024 * 1024);       // 160 KiB
  float* lp = (float*)(w + (size_t)7 * 1024 * 1024 + 256 * 1024);  // 160 KiB
  float* Op = (float*)(w + (size_t)8 * 1024 * 1024);       // 10.5 MiB

  prep_w<<<48, 256, 0, stream>>>(Wq, Wk, Wv, Wt);
  qkv_kernel<<<512, 256, 0, stream>>>(x, Wt, qb, kb, vT);
  attn_partial<<<2560, 64, 0, stream>>>(qb, kb, vT, Op, mp, lp);
  attn_combine<<<dim3(256, 4), 256, 0, stream>>>(Op, mp, lp, out);
}

// Round 5
// 129.749 us; speedup vs baseline: 2.1313x; 1.1506x over previous
//
#include <hip/hip_runtime.h>
#include <hip/hip_bf16.h>
#include <math.h>

typedef __attribute__((ext_vector_type(8))) short bf16x8;
typedef __attribute__((ext_vector_type(4))) float f32x4;
typedef __attribute__((ext_vector_type(16))) float f32x16;
typedef __attribute__((ext_vector_type(2))) unsigned uint2v;

#define MFMA16(A, B, C) __builtin_amdgcn_mfma_f32_16x16x32_bf16(A, B, C, 0, 0, 0)
#define MFMA32(A, B, C) __builtin_amdgcn_mfma_f32_32x32x16_bf16(A, B, C, 0, 0, 0)
#define LOG2E 1.44269504f

__device__ __forceinline__ short f2bf(float f) {
  union { __hip_bfloat16 b; short s; } v;
  v.b = __float2bfloat16(f);
  return v.s;
}

__device__ __forceinline__ float bf2f(short s) {
  union { unsigned u; float f; } v;
  v.u = ((unsigned)(unsigned short)s) << 16;
  return v.f;
}

__device__ __forceinline__ bf16x8 cvt8(float4 a, float4 b) {
  bf16x8 r;
  r[0] = f2bf(a.x); r[1] = f2bf(a.y); r[2] = f2bf(a.z); r[3] = f2bf(a.w);
  r[4] = f2bf(b.x); r[5] = f2bf(b.y); r[6] = f2bf(b.z); r[7] = f2bf(b.w);
  return r;
}

__device__ __forceinline__ unsigned cvt_pk(float lo, float hi) {
  unsigned r;
  asm("v_cvt_pk_bf16_f32 %0, %1, %2" : "=v"(r) : "v"(lo), "v"(hi));
  return r;
}

// permlane32_swap(a,b) -> {a.lo||b.lo, a.hi||b.hi} (VDST rows 2,3 <-> VSRC rows 0,1)
__device__ __forceinline__ float xhalf_max(float x) {
  uint2v r = __builtin_amdgcn_permlane32_swap(__float_as_uint(x), __float_as_uint(x),
                                              false, false);
  return fmaxf(__uint_as_float(r[0]), __uint_as_float(r[1]));
}
__device__ __forceinline__ float xhalf_sum(float x) {
  uint2v r = __builtin_amdgcn_permlane32_swap(__float_as_uint(x), __float_as_uint(x),
                                              false, false);
  return __uint_as_float(r[0]) + __uint_as_float(r[1]);
}

// ---------------- weight transpose via LDS tiles: Wt[n][d] bf16, n in [0,192)
__global__ __launch_bounds__(256) void prep_w(const float* __restrict__ Wq,
                                              const float* __restrict__ Wk,
                                              const float* __restrict__ Wv,
                                              short* __restrict__ Wt) {
  __shared__ float ls[64][65];
  const int wsel = blockIdx.x >> 4;
  const int dt = blockIdx.x & 15;
  const float* W = (wsel == 0) ? Wq : ((wsel == 1) ? Wk : Wv);
  const float scale = (wsel == 0) ? 0.03125f : 1.0f;
  const int d0 = dt * 64;
  const int rr = threadIdx.x >> 4;
  const int cc = threadIdx.x & 15;
#pragma unroll
  for (int p = 0; p < 4; ++p) {
    int d = rr + p * 16;
    float4 v = *(const float4*)(W + (size_t)(d0 + d) * 64 + cc * 4);
    ls[d][cc * 4 + 0] = v.x; ls[d][cc * 4 + 1] = v.y;
    ls[d][cc * 4 + 2] = v.z; ls[d][cc * 4 + 3] = v.w;
  }
  __syncthreads();
#pragma unroll
  for (int p = 0; p < 4; ++p) {
    int h = rr + p * 16;
    short4 o;
    o.x = f2bf(ls[cc * 4 + 0][h] * scale);
    o.y = f2bf(ls[cc * 4 + 1][h] * scale);
    o.z = f2bf(ls[cc * 4 + 2][h] * scale);
    o.w = f2bf(ls[cc * 4 + 3][h] * scale);
    *(short4*)(Wt + (size_t)(wsel * 64 + h) * 1024 + d0 + cc * 4) = o;
  }
}

// ---------------- fused QKV projection: 1024 blocks x 16 rows, 4 waves/SIMD.
// Wave w -> nt tiles w*3..w*3+2; 2-stage register pipeline, barrier-free.
__global__ __launch_bounds__(256) void qkv_kernel(const float* __restrict__ x,
                                                  const short* __restrict__ Wt,
                                                  short* __restrict__ qo,
                                                  short* __restrict__ ko,
                                                  short* __restrict__ vT) {
  const int m0 = blockIdx.x * 16;
  const int wave = threadIdx.x >> 6, lane = threadIdx.x & 63;
  const int lr = lane & 15, lq = lane >> 4;

  const f32x4 fzero = {0.f, 0.f, 0.f, 0.f};
  f32x4 acc[3];
#pragma unroll
  for (int i = 0; i < 3; ++i) acc[i] = fzero;

  const float* xr = x + (size_t)(m0 + lr) * 1024 + lq * 8;
  const short* wb = Wt + (size_t)(wave * 48 + lr) * 1024 + lq * 8;

#define LOADX(X0, X1, kk)                       \
  X0 = *(const float4*)(xr + (kk));             \
  X1 = *(const float4*)(xr + (kk) + 4);
#define LOADW(B0, B1, B2, kk)                   \
  B0 = *(const bf16x8*)(wb + (kk));             \
  B1 = *(const bf16x8*)(wb + 16 * 1024 + (kk)); \
  B2 = *(const bf16x8*)(wb + 32 * 1024 + (kk));

  float4 ax0, ax1, bx0, bx1;
  bf16x8 aw0, aw1, aw2, bw0, bw1, bw2;
  LOADX(ax0, ax1, 0) LOADW(aw0, aw1, aw2, 0)
  LOADX(bx0, bx1, 32) LOADW(bw0, bw1, bw2, 32)

  for (int k0 = 0; k0 < 1024; k0 += 64) {
    {
      bf16x8 af = cvt8(ax0, ax1);
      bf16x8 u0 = aw0, u1 = aw1, u2 = aw2;
      if (k0 + 64 < 1024) { LOADX(ax0, ax1, k0 + 64) LOADW(aw0, aw1, aw2, k0 + 64) }
      acc[0] = MFMA16(af, u0, acc[0]);
      acc[1] = MFMA16(af, u1, acc[1]);
      acc[2] = MFMA16(af, u2, acc[2]);
    }
    {
      bf16x8 af = cvt8(bx0, bx1);
      bf16x8 u0 = bw0, u1 = bw1, u2 = bw2;
      if (k0 + 96 < 1024) { LOADX(bx0, bx1, k0 + 96) LOADW(bw0, bw1, bw2, k0 + 96) }
      acc[0] = MFMA16(af, u0, acc[0]);
      acc[1] = MFMA16(af, u1, acc[1]);
      acc[2] = MFMA16(af, u2, acc[2]);
    }
  }
#undef LOADX
#undef LOADW

#pragma unroll
  for (int jj = 0; jj < 3; ++jj) {
    int nt = wave * 3 + jj;
#pragma unroll
    for (int r = 0; r < 4; ++r) {
      int m = m0 + lq * 4 + r;  // C/D: row=(lane>>4)*4+reg
      int n = nt * 16 + lr;     //      col=lane&15
      short hval = f2bf(acc[jj][r]);
      if (nt < 4) qo[m * 64 + n] = hval;
      else if (nt < 8) ko[m * 64 + (n - 64)] = hval;
      else vT[((m >> 12) << 18) + ((n - 128) << 12) + (m & 4095)] = hval;
    }
  }
}

// ---------------- split-K causal flash, swapped-QK^T 32x32, LDS-free.
// Units: (b, 32-row group g 0..127, 512-wide segment s), 576/batch, 2304 blocks.
// Lane owns q-col = lane&31; softmax fully in-register; partial O stored bf16.
__global__ __launch_bounds__(64, 2) void attn_partial(const short* __restrict__ qbuf,
                                                      const short* __restrict__ kbuf,
                                                      const short* __restrict__ vbuf,
                                                      short* __restrict__ Op,
                                                      float* __restrict__ mp,
                                                      float* __restrict__ lp) {
  const int id = blockIdx.x;
  const int b = (id & 7) >> 1;                 // 2 XCDs per batch
  const int u = ((id >> 3) << 1) | (id & 1);   // 0..575
  int j = 0;
  while (u >= 8 * (j + 1) * (j + 2)) ++j;      // tier: nseg = j+1
  const int t = u - 8 * j * (j + 1);
  const int gl = t / (j + 1);
  const int s = t - gl * (j + 1);
  const int g = (j << 4) + gl;
  const int qr0 = g << 5;
  const int kv_lo = s << 9;
  const int kv_hi = (s == j) ? (qr0 + 32) : ((s + 1) << 9);

  const int lane = threadIdx.x;
  const int l31 = lane & 31, hi = lane >> 5;
  const int qglob = qr0 + l31;

  const short* qb = qbuf + ((size_t)b << 18);
  const short* kb = kbuf + ((size_t)b << 18);
  const short* vb = vbuf + ((size_t)b << 18);

  bf16x8 bq[4];  // Q as B-operand: lane holds col q=l31, k = c*16 + hi*8 ..+7
#pragma unroll
  for (int c = 0; c < 4; ++c)
    bq[c] = *(const bf16x8*)(qb + (size_t)(qr0 + l31) * 64 + c * 16 + hi * 8);

  f32x16 o0, o1;
#pragma unroll
  for (int r = 0; r < 16; ++r) { o0[r] = 0.f; o1[r] = 0.f; }
  float mrow = -1e30f, lrow = 0.f;

  union U8 { unsigned u[4]; bf16x8 v; };

  for (int kv0 = kv_lo; kv0 < kv_hi; kv0 += 64) {
    const int kv1 = kv0 + 32;
    // ---- K A-frags (lane = kv row l31, k = hd hi*8..) + V A-frags (early)
    bf16x8 ka[4], kc[4], va[8];
#pragma unroll
    for (int c = 0; c < 4; ++c) {
      ka[c] = *(const bf16x8*)(kb + (size_t)(kv0 + l31) * 64 + c * 16 + hi * 8);
      kc[c] = *(const bf16x8*)(kb + (size_t)(kv1 + l31) * 64 + c * 16 + hi * 8);
    }
#pragma unroll
    for (int h = 0; h < 2; ++h) {
      const short* vrow = vb + (size_t)(32 * h + l31) * 4096;
      va[h * 4 + 0] = *(const bf16x8*)(vrow + kv0 + hi * 8);
      va[h * 4 + 1] = *(const bf16x8*)(vrow + kv0 + 16 + hi * 8);
      va[h * 4 + 2] = *(const bf16x8*)(vrow + kv1 + hi * 8);
      va[h * 4 + 3] = *(const bf16x8*)(vrow + kv1 + 16 + hi * 8);
    }

    // ---- S^T = K Q^T : lane holds q-col l31, kv rows (r&3)+8*(r>>2)+4*hi
    f32x16 s0, s1;
#pragma unroll
    for (int r = 0; r < 16; ++r) { s0[r] = 0.f; s1[r] = 0.f; }
#pragma unroll
    for (int c = 0; c < 4; ++c) {
      s0 = MFMA32(ka[c], bq[c], s0);
      s1 = MFMA32(kc[c], bq[c], s1);
    }

    // ---- causal mask (diagonal tiles only; padding tiles fully masked)
    if (kv0 + 31 > qr0) {
#pragma unroll
      for (int r = 0; r < 16; ++r)
        if (kv0 + (r & 3) + 8 * (r >> 2) + 4 * hi > qglob) s0[r] = -1e30f;
    }
    if (kv1 + 31 > qr0) {
#pragma unroll
      for (int r = 0; r < 16; ++r)
        if (kv1 + (r & 3) + 8 * (r >> 2) + 4 * hi > qglob) s1[r] = -1e30f;
    }

    // ---- in-register max tree + one cross-half swap
    float m8[8];
#pragma unroll
    for (int r = 0; r < 8; ++r)
      m8[r] = fmaxf(fmaxf(s0[r], s0[r + 8]), fmaxf(s1[r], s1[r + 8]));
    float pm = fmaxf(fmaxf(fmaxf(m8[0], m8[4]), fmaxf(m8[1], m8[5])),
                     fmaxf(fmaxf(m8[2], m8[6]), fmaxf(m8[3], m8[7])));
    pm = xhalf_max(pm);

    if (!__all(pm - mrow <= 8.0f)) {  // defer-max (T13)
      float mn = fmaxf(mrow, pm);
      float sc = exp2f((mrow - mn) * LOG2E);
      lrow *= sc;
#pragma unroll
      for (int r = 0; r < 16; ++r) { o0[r] *= sc; o1[r] *= sc; }
      mrow = mn;
    }

    float p0[16], p1[16];
#pragma unroll
    for (int r = 0; r < 16; ++r) {
      p0[r] = exp2f((s0[r] - mrow) * LOG2E);
      p1[r] = exp2f((s1[r] - mrow) * LOG2E);
    }
    float a8[8];
#pragma unroll
    for (int r = 0; r < 8; ++r) a8[r] = (p0[r] + p0[r + 8]) + (p1[r] + p1[r + 8]);
    float s4 = ((a8[0] + a8[4]) + (a8[1] + a8[5])) + ((a8[2] + a8[6]) + (a8[3] + a8[7]));
    lrow += xhalf_sum(s4);

    // ---- P -> bf16 B-frags via cvt_pk + permlane32_swap (T12).
    // Lane(hi) holds kv pairs: c0..c7 = (0,1)(2,3)(8,9)(10,11)(16,17)(18,19)
    // (24,25)(26,27) for hi=0; +4 for hi=1. Need u[e]=kv(hi*8+2e, +1).
    // swap(cX,cY) = {cX.lo||cY.lo, cX.hi||cY.hi}:
    //   swap(c0,c2) -> (u0, u2); swap(c1,c3) -> (u1, u3)  [chunk kv 0..15]
    //   swap(c4,c6) -> (u0, u2); swap(c5,c7) -> (u1, u3)  [chunk kv 16..31]
#define MAKE_FRAGS(P, UA, UB)                                                  \
    {                                                                          \
      unsigned c0 = cvt_pk(P[0], P[1]), c1 = cvt_pk(P[2], P[3]);               \
      unsigned c2 = cvt_pk(P[4], P[5]), c3 = cvt_pk(P[6], P[7]);               \
      unsigned c4 = cvt_pk(P[8], P[9]), c5 = cvt_pk(P[10], P[11]);             \
      unsigned c6 = cvt_pk(P[12], P[13]), c7 = cvt_pk(P[14], P[15]);           \
      uint2v rA = __builtin_amdgcn_permlane32_swap(c0, c2, false, false);      \
      uint2v rB = __builtin_amdgcn_permlane32_swap(c1, c3, false, false);      \
      uint2v rC = __builtin_amdgcn_permlane32_swap(c4, c6, false, false);      \
      uint2v rD = __builtin_amdgcn_permlane32_swap(c5, c7, false, false);      \
      UA.u[0] = rA[0]; UA.u[2] = rA[1];                                        \
      UA.u[1] = rB[0]; UA.u[3] = rB[1];                                        \
      UB.u[0] = rC[0]; UB.u[2] = rC[1];                                        \
      UB.u[1] = rD[0]; UB.u[3] = rD[1];                                        \
    }
    U8 pa00, pa01, pa10, pa11;
    MAKE_FRAGS(p0, pa00, pa01)
    MAKE_FRAGS(p1, pa10, pa11)
#undef MAKE_FRAGS

    // ---- O^T += V^T P^T
    o0 = MFMA32(va[0], pa00.v, o0);
    o0 = MFMA32(va[1], pa01.v, o0);
    o0 = MFMA32(va[2], pa10.v, o0);
    o0 = MFMA32(va[3], pa11.v, o0);
    o1 = MFMA32(va[4], pa00.v, o1);
    o1 = MFMA32(va[5], pa01.v, o1);
    o1 = MFMA32(va[6], pa10.v, o1);
    o1 = MFMA32(va[7], pa11.v, o1);
  }

  // ---- store partials: Op[pid][hd 64][q 32] bf16 (coalesced), m/l per q
  const int pid = b * 576 + u;
  short* Ob = Op + (size_t)pid * 2048;
#pragma unroll
  for (int r = 0; r < 16; ++r) {
    int hd = (r & 3) + 8 * (r >> 2) + 4 * hi;
    Ob[hd * 32 + l31] = f2bf(o0[r]);
    Ob[(32 + hd) * 32 + l31] = f2bf(o1[r]);
  }
  if (hi == 0) {
    mp[pid * 32 + l31] = mrow;
    lp[pid * 32 + l31] = lrow;
  }
}

// ---------------- combine <=8 segment partials per (b,g); LDS transpose out
__global__ __launch_bounds__(256) void attn_combine(const short* __restrict__ Op,
                                                    const float* __restrict__ mp,
                                                    const float* __restrict__ lp,
                                                    float* __restrict__ out) {
  __shared__ float ls[64][33];
  const int g = blockIdx.x;  // 0..127
  const int b = blockIdx.y;  // 0..3
  const int j = g >> 4;
  const int nseg = j + 1;
  const int base = b * 576 + 8 * j * (j + 1) + (g - (j << 4)) * (j + 1);
  const int qc = threadIdx.x & 31, hg = threadIdx.x >> 5;  // hg 0..7

  float mm = -1e30f;
  for (int s2 = 0; s2 < nseg; ++s2) mm = fmaxf(mm, mp[(base + s2) * 32 + qc]);
  float lsum = 0.f;
  float osum[8];
#pragma unroll
  for (int it = 0; it < 8; ++it) osum[it] = 0.f;
  for (int s2 = 0; s2 < nseg; ++s2) {
    float w = exp2f((mp[(base + s2) * 32 + qc] - mm) * LOG2E);
    lsum += lp[(base + s2) * 32 + qc] * w;
    const short* Ob = Op + (size_t)(base + s2) * 2048;
#pragma unroll
    for (int it = 0; it < 8; ++it)
      osum[it] += bf2f(Ob[(hg * 8 + it) * 32 + qc]) * w;
  }
  float inv = 1.0f / lsum;
#pragma unroll
  for (int it = 0; it < 8; ++it) ls[hg * 8 + it][qc] = osum[it] * inv;
  __syncthreads();
  const int lane = threadIdx.x & 63, qq = threadIdx.x >> 6;
#pragma unroll
  for (int p = 0; p < 8; ++p) {
    int qrow = qq * 8 + p;
    out[((size_t)b * 4096 + (size_t)g * 32 + qrow) * 64 + lane] = ls[lane][qrow];
  }
}

extern "C" void kernel_launch(void* const* d_in, const int* in_sizes, int n_in,
                              void* d_out, int out_size, void* d_ws, size_t ws_size,
                              hipStream_t stream) {
  const float* x = (const float*)d_in[0];
  const float* Wq = (const float*)d_in[1];
  const float* Wk = (const float*)d_in[2];
  const float* Wv = (const float*)d_in[3];
  float* out = (float*)d_out;

  char* w = (char*)d_ws;
  short* qb = (short*)(w);                                       // 2 MiB
  short* kb = (short*)(w + (size_t)2 * 1024 * 1024);             // 2 MiB
  short* vT = (short*)(w + (size_t)4 * 1024 * 1024);             // 2 MiB
  short* Wt = (short*)(w + (size_t)6 * 1024 * 1024);             // 384 KiB
  float* mp = (float*)(w + (size_t)6656 * 1024);                 // 288 KiB
  float* lp = (float*)(w + (size_t)7040 * 1024);                 // 288 KiB
  short* Op = (short*)(w + (size_t)7424 * 1024);                 // 9.4 MiB bf16

  prep_w<<<48, 256, 0, stream>>>(Wq, Wk, Wv, Wt);
  qkv_kernel<<<1024, 256, 0, stream>>>(x, Wt, qb, kb, vT);
  attn_partial<<<2304, 64, 0, stream>>>(qb, kb, vT, Op, mp, lp);
  attn_combine<<<dim3(128, 4), 256, 0, stream>>>(Op, mp, lp, out);
}

// Round 6
// 129.102 us; speedup vs baseline: 2.1420x; 1.0050x over previous
//
#include <hip/hip_runtime.h>
#include <hip/hip_bf16.h>
#include <math.h>

typedef __attribute__((ext_vector_type(8))) short bf16x8;
typedef __attribute__((ext_vector_type(4))) float f32x4;
typedef __attribute__((ext_vector_type(16))) float f32x16;
typedef __attribute__((ext_vector_type(2))) unsigned uint2v;

#define MFMA16(A, B, C) __builtin_amdgcn_mfma_f32_16x16x32_bf16(A, B, C, 0, 0, 0)
#define MFMA32(A, B, C) __builtin_amdgcn_mfma_f32_32x32x16_bf16(A, B, C, 0, 0, 0)
#define LOG2E 1.44269504f

__device__ __forceinline__ short f2bf(float f) {
  union { __hip_bfloat16 b; short s; } v;
  v.b = __float2bfloat16(f);
  return v.s;
}

__device__ __forceinline__ float bf2f(short s) {
  union { unsigned u; float f; } v;
  v.u = ((unsigned)(unsigned short)s) << 16;
  return v.f;
}

__device__ __forceinline__ bf16x8 cvt8(float4 a, float4 b) {
  bf16x8 r;
  r[0] = f2bf(a.x); r[1] = f2bf(a.y); r[2] = f2bf(a.z); r[3] = f2bf(a.w);
  r[4] = f2bf(b.x); r[5] = f2bf(b.y); r[6] = f2bf(b.z); r[7] = f2bf(b.w);
  return r;
}

__device__ __forceinline__ unsigned cvt_pk(float lo, float hi) {
  unsigned r;
  asm("v_cvt_pk_bf16_f32 %0, %1, %2" : "=v"(r) : "v"(lo), "v"(hi));
  return r;
}

// permlane32_swap(a,b) -> {a.lo||b.lo, a.hi||b.hi} (VDST rows 2,3 <-> VSRC rows 0,1)
__device__ __forceinline__ float xhalf_max(float x) {
  uint2v r = __builtin_amdgcn_permlane32_swap(__float_as_uint(x), __float_as_uint(x),
                                              false, false);
  return fmaxf(__uint_as_float(r[0]), __uint_as_float(r[1]));
}
__device__ __forceinline__ float xhalf_sum(float x) {
  uint2v r = __builtin_amdgcn_permlane32_swap(__float_as_uint(x), __float_as_uint(x),
                                              false, false);
  return __uint_as_float(r[0]) + __uint_as_float(r[1]);
}

// ---------------- weight transpose via LDS tiles: Wt[n][d] bf16, n in [0,192)
__global__ __launch_bounds__(256) void prep_w(const float* __restrict__ Wq,
                                              const float* __restrict__ Wk,
                                              const float* __restrict__ Wv,
                                              short* __restrict__ Wt) {
  __shared__ float ls[64][65];
  const int wsel = blockIdx.x >> 4;
  const int dt = blockIdx.x & 15;
  const float* W = (wsel == 0) ? Wq : ((wsel == 1) ? Wk : Wv);
  const float scale = (wsel == 0) ? 0.03125f : 1.0f;
  const int d0 = dt * 64;
  const int rr = threadIdx.x >> 4;
  const int cc = threadIdx.x & 15;
#pragma unroll
  for (int p = 0; p < 4; ++p) {
    int d = rr + p * 16;
    float4 v = *(const float4*)(W + (size_t)(d0 + d) * 64 + cc * 4);
    ls[d][cc * 4 + 0] = v.x; ls[d][cc * 4 + 1] = v.y;
    ls[d][cc * 4 + 2] = v.z; ls[d][cc * 4 + 3] = v.w;
  }
  __syncthreads();
#pragma unroll
  for (int p = 0; p < 4; ++p) {
    int h = rr + p * 16;
    short4 o;
    o.x = f2bf(ls[cc * 4 + 0][h] * scale);
    o.y = f2bf(ls[cc * 4 + 1][h] * scale);
    o.z = f2bf(ls[cc * 4 + 2][h] * scale);
    o.w = f2bf(ls[cc * 4 + 3][h] * scale);
    *(short4*)(Wt + (size_t)(wsel * 64 + h) * 1024 + d0 + cc * 4) = o;
  }
}

// ---------------- fused QKV projection: 1024 blocks x 16 rows, 4 waves/SIMD.
// Wave w -> nt tiles w*3..w*3+2; depth-4 register pipeline (Little's law:
// 4 stages x 5 loads x 16B = 320B/lane in flight), fully unrolled so all
// stage-array indices are static. Barrier-free.
__global__ __launch_bounds__(256, 4) void qkv_kernel(const float* __restrict__ x,
                                                     const short* __restrict__ Wt,
                                                     short* __restrict__ qo,
                                                     short* __restrict__ ko,
                                                     short* __restrict__ vT) {
  const int m0 = blockIdx.x * 16;
  const int wave = threadIdx.x >> 6, lane = threadIdx.x & 63;
  const int lr = lane & 15, lq = lane >> 4;

  const f32x4 fzero = {0.f, 0.f, 0.f, 0.f};
  f32x4 acc[3];
#pragma unroll
  for (int i = 0; i < 3; ++i) acc[i] = fzero;

  const float* xr = x + (size_t)(m0 + lr) * 1024 + lq * 8;
  const short* wb = Wt + (size_t)(wave * 48 + lr) * 1024 + lq * 8;

  float4 xs[4][2];
  bf16x8 ws[4][3];
#pragma unroll
  for (int st = 0; st < 4; ++st) {
    xs[st][0] = *(const float4*)(xr + st * 32);
    xs[st][1] = *(const float4*)(xr + st * 32 + 4);
    ws[st][0] = *(const bf16x8*)(wb + st * 32);
    ws[st][1] = *(const bf16x8*)(wb + 16 * 1024 + st * 32);
    ws[st][2] = *(const bf16x8*)(wb + 32 * 1024 + st * 32);
  }

#pragma unroll
  for (int kb = 0; kb < 1024; kb += 128) {
#pragma unroll
    for (int st = 0; st < 4; ++st) {
      const int k0 = kb + st * 32;
      bf16x8 af = cvt8(xs[st][0], xs[st][1]);
      bf16x8 u0 = ws[st][0], u1 = ws[st][1], u2 = ws[st][2];
      if (k0 + 128 < 1024) {  // refill this stage slot for k0+128
        xs[st][0] = *(const float4*)(xr + k0 + 128);
        xs[st][1] = *(const float4*)(xr + k0 + 132);
        ws[st][0] = *(const bf16x8*)(wb + k0 + 128);
        ws[st][1] = *(const bf16x8*)(wb + 16 * 1024 + k0 + 128);
        ws[st][2] = *(const bf16x8*)(wb + 32 * 1024 + k0 + 128);
      }
      acc[0] = MFMA16(af, u0, acc[0]);
      acc[1] = MFMA16(af, u1, acc[1]);
      acc[2] = MFMA16(af, u2, acc[2]);
    }
  }

#pragma unroll
  for (int jj = 0; jj < 3; ++jj) {
    int nt = wave * 3 + jj;
#pragma unroll
    for (int r = 0; r < 4; ++r) {
      int m = m0 + lq * 4 + r;  // C/D: row=(lane>>4)*4+reg
      int n = nt * 16 + lr;     //      col=lane&15
      short hval = f2bf(acc[jj][r]);
      if (nt < 4) qo[m * 64 + n] = hval;
      else if (nt < 8) ko[m * 64 + (n - 64)] = hval;
      else vT[((m >> 12) << 18) + ((n - 128) << 12) + (m & 4095)] = hval;
    }
  }
}

// ---------------- split-K causal flash, swapped-QK^T 32x32, LDS-free.
// Units: (b, 32-row group g 0..127, 512-wide segment s), 576/batch, 2304 blocks.
// Lane owns q-col = lane&31; softmax fully in-register; partial O stored bf16.
__global__ __launch_bounds__(64, 2) void attn_partial(const short* __restrict__ qbuf,
                                                      const short* __restrict__ kbuf,
                                                      const short* __restrict__ vbuf,
                                                      short* __restrict__ Op,
                                                      float* __restrict__ mp,
                                                      float* __restrict__ lp) {
  const int id = blockIdx.x;
  const int b = (id & 7) >> 1;                 // 2 XCDs per batch
  const int u = ((id >> 3) << 1) | (id & 1);   // 0..575
  int j = 0;
  while (u >= 8 * (j + 1) * (j + 2)) ++j;      // tier: nseg = j+1
  const int t = u - 8 * j * (j + 1);
  const int gl = t / (j + 1);
  const int s = t - gl * (j + 1);
  const int g = (j << 4) + gl;
  const int qr0 = g << 5;
  const int kv_lo = s << 9;
  const int kv_hi = (s == j) ? (qr0 + 32) : ((s + 1) << 9);

  const int lane = threadIdx.x;
  const int l31 = lane & 31, hi = lane >> 5;
  const int qglob = qr0 + l31;

  const short* qb = qbuf + ((size_t)b << 18);
  const short* kb = kbuf + ((size_t)b << 18);
  const short* vb = vbuf + ((size_t)b << 18);

  bf16x8 bq[4];  // Q as B-operand: lane holds col q=l31, k = c*16 + hi*8 ..+7
#pragma unroll
  for (int c = 0; c < 4; ++c)
    bq[c] = *(const bf16x8*)(qb + (size_t)(qr0 + l31) * 64 + c * 16 + hi * 8);

  f32x16 o0, o1;
#pragma unroll
  for (int r = 0; r < 16; ++r) { o0[r] = 0.f; o1[r] = 0.f; }
  float mrow = -1e30f, lrow = 0.f;

  union U8 { unsigned u[4]; bf16x8 v; };

  for (int kv0 = kv_lo; kv0 < kv_hi; kv0 += 64) {
    const int kv1 = kv0 + 32;
    // ---- K A-frags (lane = kv row l31, k = hd hi*8..) + V A-frags (early)
    bf16x8 ka[4], kc[4], va[8];
#pragma unroll
    for (int c = 0; c < 4; ++c) {
      ka[c] = *(const bf16x8*)(kb + (size_t)(kv0 + l31) * 64 + c * 16 + hi * 8);
      kc[c] = *(const bf16x8*)(kb + (size_t)(kv1 + l31) * 64 + c * 16 + hi * 8);
    }
#pragma unroll
    for (int h = 0; h < 2; ++h) {
      const short* vrow = vb + (size_t)(32 * h + l31) * 4096;
      va[h * 4 + 0] = *(const bf16x8*)(vrow + kv0 + hi * 8);
      va[h * 4 + 1] = *(const bf16x8*)(vrow + kv0 + 16 + hi * 8);
      va[h * 4 + 2] = *(const bf16x8*)(vrow + kv1 + hi * 8);
      va[h * 4 + 3] = *(const bf16x8*)(vrow + kv1 + 16 + hi * 8);
    }

    // ---- S^T = K Q^T : lane holds q-col l31, kv rows (r&3)+8*(r>>2)+4*hi
    f32x16 s0, s1;
#pragma unroll
    for (int r = 0; r < 16; ++r) { s0[r] = 0.f; s1[r] = 0.f; }
#pragma unroll
    for (int c = 0; c < 4; ++c) {
      s0 = MFMA32(ka[c], bq[c], s0);
      s1 = MFMA32(kc[c], bq[c], s1);
    }

    // ---- causal mask (diagonal tiles only; padding tiles fully masked)
    if (kv0 + 31 > qr0) {
#pragma unroll
      for (int r = 0; r < 16; ++r)
        if (kv0 + (r & 3) + 8 * (r >> 2) + 4 * hi > qglob) s0[r] = -1e30f;
    }
    if (kv1 + 31 > qr0) {
#pragma unroll
      for (int r = 0; r < 16; ++r)
        if (kv1 + (r & 3) + 8 * (r >> 2) + 4 * hi > qglob) s1[r] = -1e30f;
    }

    // ---- in-register max tree + one cross-half swap
    float m8[8];
#pragma unroll
    for (int r = 0; r < 8; ++r)
      m8[r] = fmaxf(fmaxf(s0[r], s0[r + 8]), fmaxf(s1[r], s1[r + 8]));
    float pm = fmaxf(fmaxf(fmaxf(m8[0], m8[4]), fmaxf(m8[1], m8[5])),
                     fmaxf(fmaxf(m8[2], m8[6]), fmaxf(m8[3], m8[7])));
    pm = xhalf_max(pm);

    if (!__all(pm - mrow <= 8.0f)) {  // defer-max (T13)
      float mn = fmaxf(mrow, pm);
      float sc = exp2f((mrow - mn) * LOG2E);
      lrow *= sc;
#pragma unroll
      for (int r = 0; r < 16; ++r) { o0[r] *= sc; o1[r] *= sc; }
      mrow = mn;
    }

    float p0[16], p1[16];
#pragma unroll
    for (int r = 0; r < 16; ++r) {
      p0[r] = exp2f((s0[r] - mrow) * LOG2E);
      p1[r] = exp2f((s1[r] - mrow) * LOG2E);
    }
    float a8[8];
#pragma unroll
    for (int r = 0; r < 8; ++r) a8[r] = (p0[r] + p0[r + 8]) + (p1[r] + p1[r + 8]);
    float s4 = ((a8[0] + a8[4]) + (a8[1] + a8[5])) + ((a8[2] + a8[6]) + (a8[3] + a8[7]));
    lrow += xhalf_sum(s4);

    // ---- P -> bf16 B-frags via cvt_pk + permlane32_swap (T12).
    // Lane(hi) holds kv pairs: c0..c7 = (0,1)(2,3)(8,9)(10,11)(16,17)(18,19)
    // (24,25)(26,27) for hi=0; +4 for hi=1. Need u[e]=kv(hi*8+2e, +1).
    // swap(cX,cY) = {cX.lo||cY.lo, cX.hi||cY.hi}:
    //   swap(c0,c2) -> (u0, u2); swap(c1,c3) -> (u1, u3)  [chunk kv 0..15]
    //   swap(c4,c6) -> (u0, u2); swap(c5,c7) -> (u1, u3)  [chunk kv 16..31]
#define MAKE_FRAGS(P, UA, UB)                                                  \
    {                                                                          \
      unsigned c0 = cvt_pk(P[0], P[1]), c1 = cvt_pk(P[2], P[3]);               \
      unsigned c2 = cvt_pk(P[4], P[5]), c3 = cvt_pk(P[6], P[7]);               \
      unsigned c4 = cvt_pk(P[8], P[9]), c5 = cvt_pk(P[10], P[11]);             \
      unsigned c6 = cvt_pk(P[12], P[13]), c7 = cvt_pk(P[14], P[15]);           \
      uint2v rA = __builtin_amdgcn_permlane32_swap(c0, c2, false, false);      \
      uint2v rB = __builtin_amdgcn_permlane32_swap(c1, c3, false, false);      \
      uint2v rC = __builtin_amdgcn_permlane32_swap(c4, c6, false, false);      \
      uint2v rD = __builtin_amdgcn_permlane32_swap(c5, c7, false, false);      \
      UA.u[0] = rA[0]; UA.u[2] = rA[1];                                        \
      UA.u[1] = rB[0]; UA.u[3] = rB[1];                                        \
      UB.u[0] = rC[0]; UB.u[2] = rC[1];                                        \
      UB.u[1] = rD[0]; UB.u[3] = rD[1];                                        \
    }
    U8 pa00, pa01, pa10, pa11;
    MAKE_FRAGS(p0, pa00, pa01)
    MAKE_FRAGS(p1, pa10, pa11)
#undef MAKE_FRAGS

    // ---- O^T += V^T P^T
    o0 = MFMA32(va[0], pa00.v, o0);
    o0 = MFMA32(va[1], pa01.v, o0);
    o0 = MFMA32(va[2], pa10.v, o0);
    o0 = MFMA32(va[3], pa11.v, o0);
    o1 = MFMA32(va[4], pa00.v, o1);
    o1 = MFMA32(va[5], pa01.v, o1);
    o1 = MFMA32(va[6], pa10.v, o1);
    o1 = MFMA32(va[7], pa11.v, o1);
  }

  // ---- store partials: Op[pid][hd 64][q 32] bf16 (coalesced), m/l per q
  const int pid = b * 576 + u;
  short* Ob = Op + (size_t)pid * 2048;
#pragma unroll
  for (int r = 0; r < 16; ++r) {
    int hd = (r & 3) + 8 * (r >> 2) + 4 * hi;
    Ob[hd * 32 + l31] = f2bf(o0[r]);
    Ob[(32 + hd) * 32 + l31] = f2bf(o1[r]);
  }
  if (hi == 0) {
    mp[pid * 32 + l31] = mrow;
    lp[pid * 32 + l31] = lrow;
  }
}

// ---------------- combine <=8 segment partials per (b,g); LDS transpose out
__global__ __launch_bounds__(256) void attn_combine(const short* __restrict__ Op,
                                                    const float* __restrict__ mp,
                                                    const float* __restrict__ lp,
                                                    float* __restrict__ out) {
  __shared__ float ls[64][33];
  const int g = blockIdx.x;  // 0..127
  const int b = blockIdx.y;  // 0..3
  const int j = g >> 4;
  const int nseg = j + 1;
  const int base = b * 576 + 8 * j * (j + 1) + (g - (j << 4)) * (j + 1);
  const int qc = threadIdx.x & 31, hg = threadIdx.x >> 5;  // hg 0..7

  float mm = -1e30f;
  for (int s2 = 0; s2 < nseg; ++s2) mm = fmaxf(mm, mp[(base + s2) * 32 + qc]);
  float lsum = 0.f;
  float osum[8];
#pragma unroll
  for (int it = 0; it < 8; ++it) osum[it] = 0.f;
  for (int s2 = 0; s2 < nseg; ++s2) {
    float w = exp2f((mp[(base + s2) * 32 + qc] - mm) * LOG2E);
    lsum += lp[(base + s2) * 32 + qc] * w;
    const short* Ob = Op + (size_t)(base + s2) * 2048;
#pragma unroll
    for (int it = 0; it < 8; ++it)
      osum[it] += bf2f(Ob[(hg * 8 + it) * 32 + qc]) * w;
  }
  float inv = 1.0f / lsum;
#pragma unroll
  for (int it = 0; it < 8; ++it) ls[hg * 8 + it][qc] = osum[it] * inv;
  __syncthreads();
  const int lane = threadIdx.x & 63, qq = threadIdx.x >> 6;
#pragma unroll
  for (int p = 0; p < 8; ++p) {
    int qrow = qq * 8 + p;
    out[((size_t)b * 4096 + (size_t)g * 32 + qrow) * 64 + lane] = ls[lane][qrow];
  }
}

extern "C" void kernel_launch(void* const* d_in, const int* in_sizes, int n_in,
                              void* d_out, int out_size, void* d_ws, size_t ws_size,
                              hipStream_t stream) {
  const float* x = (const float*)d_in[0];
  const float* Wq = (const float*)d_in[1];
  const float* Wk = (const float*)d_in[2];
  const float* Wv = (const float*)d_in[3];
  float* out = (float*)d_out;

  char* w = (char*)d_ws;
  short* qb = (short*)(w);                                       // 2 MiB
  short* kb = (short*)(w + (size_t)2 * 1024 * 1024);             // 2 MiB
  short* vT = (short*)(w + (size_t)4 * 1024 * 1024);             // 2 MiB
  short* Wt = (short*)(w + (size_t)6 * 1024 * 1024);             // 384 KiB
  float* mp = (float*)(w + (size_t)6656 * 1024);                 // 288 KiB
  float* lp = (float*)(w + (size_t)7040 * 1024);                 // 288 KiB
  short* Op = (short*)(w + (size_t)7424 * 1024);                 // 9.4 MiB bf16

  prep_w<<<48, 256, 0, stream>>>(Wq, Wk, Wv, Wt);
  qkv_kernel<<<1024, 256, 0, stream>>>(x, Wt, qb, kb, vT);
  attn_partial<<<2304, 64, 0, stream>>>(qb, kb, vT, Op, mp, lp);
  attn_combine<<<dim3(128, 4), 256, 0, stream>>>(Op, mp, lp, out);
}

// Round 7
// 117.786 us; speedup vs baseline: 2.3478x; 1.0961x over previous
//
#include <hip/hip_runtime.h>
#include <hip/hip_bf16.h>
#include <math.h>

typedef __attribute__((ext_vector_type(8))) short bf16x8;
typedef __attribute__((ext_vector_type(4))) float f32x4;
typedef __attribute__((ext_vector_type(16))) float f32x16;
typedef __attribute__((ext_vector_type(2))) unsigned uint2v;

#define MFMA16(A, B, C) __builtin_amdgcn_mfma_f32_16x16x32_bf16(A, B, C, 0, 0, 0)
#define MFMA32(A, B, C) __builtin_amdgcn_mfma_f32_32x32x16_bf16(A, B, C, 0, 0, 0)
#define LOG2E 1.44269504f

__device__ __forceinline__ short f2bf(float f) {
  union { __hip_bfloat16 b; short s; } v;
  v.b = __float2bfloat16(f);
  return v.s;
}

__device__ __forceinline__ float bf2f(short s) {
  union { unsigned u; float f; } v;
  v.u = ((unsigned)(unsigned short)s) << 16;
  return v.f;
}

__device__ __forceinline__ unsigned cvt_pk(float lo, float hi) {
  unsigned r;
  asm("v_cvt_pk_bf16_f32 %0, %1, %2" : "=v"(r) : "v"(lo), "v"(hi));
  return r;
}

// permlane32_swap(a,b) -> {a.lo||b.lo, a.hi||b.hi} (VDST rows 2,3 <-> VSRC rows 0,1)
__device__ __forceinline__ float xhalf_max(float x) {
  uint2v r = __builtin_amdgcn_permlane32_swap(__float_as_uint(x), __float_as_uint(x),
                                              false, false);
  return fmaxf(__uint_as_float(r[0]), __uint_as_float(r[1]));
}
__device__ __forceinline__ float xhalf_sum(float x) {
  uint2v r = __builtin_amdgcn_permlane32_swap(__float_as_uint(x), __float_as_uint(x),
                                              false, false);
  return __uint_as_float(r[0]) + __uint_as_float(r[1]);
}

// ---------------- weight transpose via LDS tiles: Wt[n][d] bf16, n in [0,192)
__global__ __launch_bounds__(256) void prep_w(const float* __restrict__ Wq,
                                              const float* __restrict__ Wk,
                                              const float* __restrict__ Wv,
                                              short* __restrict__ Wt) {
  __shared__ float ls[64][65];
  const int wsel = blockIdx.x >> 4;
  const int dt = blockIdx.x & 15;
  const float* W = (wsel == 0) ? Wq : ((wsel == 1) ? Wk : Wv);
  const float scale = (wsel == 0) ? 0.03125f : 1.0f;
  const int d0 = dt * 64;
  const int rr = threadIdx.x >> 4;
  const int cc = threadIdx.x & 15;
#pragma unroll
  for (int p = 0; p < 4; ++p) {
    int d = rr + p * 16;
    float4 v = *(const float4*)(W + (size_t)(d0 + d) * 64 + cc * 4);
    ls[d][cc * 4 + 0] = v.x; ls[d][cc * 4 + 1] = v.y;
    ls[d][cc * 4 + 2] = v.z; ls[d][cc * 4 + 3] = v.w;
  }
  __syncthreads();
#pragma unroll
  for (int p = 0; p < 4; ++p) {
    int h = rr + p * 16;
    short4 o;
    o.x = f2bf(ls[cc * 4 + 0][h] * scale);
    o.y = f2bf(ls[cc * 4 + 1][h] * scale);
    o.z = f2bf(ls[cc * 4 + 2][h] * scale);
    o.w = f2bf(ls[cc * 4 + 3][h] * scale);
    *(short4*)(Wt + (size_t)(wsel * 64 + h) * 1024 + d0 + cc * 4) = o;
  }
}

// ---------------- fused QKV projection v4: LDS-staged x (bf16, swizzled,
// double-buffered, 1 barrier/step), BM=64 rows/block, BK=128/step, 8 steps.
// Wave w owns rows w*16..+15 and ALL 12 nt (lock-step Wt reads -> L1 hits).
// Grid 256 x 256 thr. x read ONCE per block (no intra-block redundancy).
__global__ __launch_bounds__(256) void qkv_kernel(const float* __restrict__ x,
                                                  const short* __restrict__ Wt,
                                                  short* __restrict__ qo,
                                                  short* __restrict__ ko,
                                                  short* __restrict__ vT) {
  __shared__ __align__(16) char xs[2][64 * 256];  // [buf][row 64][128 bf16]
  const int m0 = blockIdx.x * 64;
  const int tid = threadIdx.x;
  const int wave = tid >> 6, lane = tid & 63;
  const int lr = lane & 15, lq = lane >> 4;

  const f32x4 fzero = {0.f, 0.f, 0.f, 0.f};
  f32x4 acc[12];
#pragma unroll
  for (int i = 0; i < 12; ++i) acc[i] = fzero;

  // staging: thread -> row tid>>2, col-quad tid&3; load p: cols (scol+4p)*4..+3
  // (per-instr: 4 lanes cover 64B contiguous; 16 rows per wave)
  const int srow = tid >> 2, scol = tid & 3;
  const float* xg = x + (size_t)(m0 + srow) * 1024;
  const int swz_w = (srow & 7) << 4;
  char* lrow_base[2] = {xs[0] + srow * 256, xs[1] + srow * 256};

  // A-frag read ptrs: row = wave*16+lr, byte = kc*64 + lq*16 (^ swizzle)
  const int arow = wave * 16 + lr;
  const int swz_r = (arow & 7) << 4;
  const char* ard[2] = {xs[0] + arow * 256, xs[1] + arow * 256};

  // Wt base: frag(nt,kc) at wtb + nt*16*1024 + k0 + kc*32
  const short* wtb = Wt + (size_t)lr * 1024 + lq * 8;

  float4 g[8];
#define XLOAD(k0)                                                   \
  _Pragma("unroll") for (int p = 0; p < 8; ++p)                     \
      g[p] = *(const float4*)(xg + (k0) + (scol + 4 * p) * 4);
#define XWRITE(dst)                                                 \
  _Pragma("unroll") for (int p = 0; p < 8; ++p) {                   \
    short4 h;                                                       \
    h.x = f2bf(g[p].x); h.y = f2bf(g[p].y);                         \
    h.z = f2bf(g[p].z); h.w = f2bf(g[p].w);                         \
    *(short4*)((dst) + (((scol + 4 * p) * 8) ^ swz_w)) = h;         \
  }

  XLOAD(0)
  XWRITE(lrow_base[0])
  __syncthreads();

  for (int s = 0; s < 8; ++s) {
    const int cur = s & 1;
    if (s < 7) { XLOAD((s + 1) * 128) }  // prefetch next tile (oldest vmem ops)
    const int k0 = s * 128;
#pragma unroll
    for (int kc = 0; kc < 4; ++kc) {
      bf16x8 af = *(const bf16x8*)(ard[cur] + ((kc * 64 + lq * 16) ^ swz_r));
      bf16x8 bf[12];
#pragma unroll
      for (int nt = 0; nt < 12; ++nt)
        bf[nt] = *(const bf16x8*)(wtb + nt * 16384 + k0 + kc * 32);
#pragma unroll
      for (int nt = 0; nt < 12; ++nt) acc[nt] = MFMA16(af, bf[nt], acc[nt]);
    }
    if (s < 7) { XWRITE(lrow_base[cur ^ 1]) }
    __syncthreads();
  }
#undef XLOAD
#undef XWRITE

#pragma unroll
  for (int nt = 0; nt < 12; ++nt) {
#pragma unroll
    for (int r = 0; r < 4; ++r) {
      int m = m0 + wave * 16 + lq * 4 + r;  // C/D: row=(lane>>4)*4+reg
      int n = nt * 16 + lr;                 //      col=lane&15
      short hval = f2bf(acc[nt][r]);
      if (nt < 4) qo[m * 64 + n] = hval;
      else if (nt < 8) ko[m * 64 + (n - 64)] = hval;
      else vT[((m >> 12) << 18) + ((n - 128) << 12) + (m & 4095)] = hval;
    }
  }
}

// ---------------- split-K causal flash, swapped-QK^T 32x32, LDS-free.
// Units: (b, 32-row group g 0..127, 512-wide segment s), 576/batch, 2304 blocks.
// Lane owns q-col = lane&31; softmax fully in-register; partial O stored bf16.
__global__ __launch_bounds__(64, 2) void attn_partial(const short* __restrict__ qbuf,
                                                      const short* __restrict__ kbuf,
                                                      const short* __restrict__ vbuf,
                                                      short* __restrict__ Op,
                                                      float* __restrict__ mp,
                                                      float* __restrict__ lp) {
  const int id = blockIdx.x;
  const int b = (id & 7) >> 1;                 // 2 XCDs per batch
  const int u = ((id >> 3) << 1) | (id & 1);   // 0..575
  int j = 0;
  while (u >= 8 * (j + 1) * (j + 2)) ++j;      // tier: nseg = j+1
  const int t = u - 8 * j * (j + 1);
  const int gl = t / (j + 1);
  const int s = t - gl * (j + 1);
  const int g = (j << 4) + gl;
  const int qr0 = g << 5;
  const int kv_lo = s << 9;
  const int kv_hi = (s == j) ? (qr0 + 32) : ((s + 1) << 9);

  const int lane = threadIdx.x;
  const int l31 = lane & 31, hi = lane >> 5;
  const int qglob = qr0 + l31;

  const short* qb = qbuf + ((size_t)b << 18);
  const short* kb = kbuf + ((size_t)b << 18);
  const short* vb = vbuf + ((size_t)b << 18);

  bf16x8 bq[4];  // Q as B-operand: lane holds col q=l31, k = c*16 + hi*8 ..+7
#pragma unroll
  for (int c = 0; c < 4; ++c)
    bq[c] = *(const bf16x8*)(qb + (size_t)(qr0 + l31) * 64 + c * 16 + hi * 8);

  f32x16 o0, o1;
#pragma unroll
  for (int r = 0; r < 16; ++r) { o0[r] = 0.f; o1[r] = 0.f; }
  float mrow = -1e30f, lrow = 0.f;

  union U8 { unsigned u[4]; bf16x8 v; };

  for (int kv0 = kv_lo; kv0 < kv_hi; kv0 += 64) {
    const int kv1 = kv0 + 32;
    // ---- K A-frags (lane = kv row l31, k = hd hi*8..) + V A-frags (early)
    bf16x8 ka[4], kc[4], va[8];
#pragma unroll
    for (int c = 0; c < 4; ++c) {
      ka[c] = *(const bf16x8*)(kb + (size_t)(kv0 + l31) * 64 + c * 16 + hi * 8);
      kc[c] = *(const bf16x8*)(kb + (size_t)(kv1 + l31) * 64 + c * 16 + hi * 8);
    }
#pragma unroll
    for (int h = 0; h < 2; ++h) {
      const short* vrow = vb + (size_t)(32 * h + l31) * 4096;
      va[h * 4 + 0] = *(const bf16x8*)(vrow + kv0 + hi * 8);
      va[h * 4 + 1] = *(const bf16x8*)(vrow + kv0 + 16 + hi * 8);
      va[h * 4 + 2] = *(const bf16x8*)(vrow + kv1 + hi * 8);
      va[h * 4 + 3] = *(const bf16x8*)(vrow + kv1 + 16 + hi * 8);
    }

    // ---- S^T = K Q^T : lane holds q-col l31, kv rows (r&3)+8*(r>>2)+4*hi
    f32x16 s0, s1;
#pragma unroll
    for (int r = 0; r < 16; ++r) { s0[r] = 0.f; s1[r] = 0.f; }
#pragma unroll
    for (int c = 0; c < 4; ++c) {
      s0 = MFMA32(ka[c], bq[c], s0);
      s1 = MFMA32(kc[c], bq[c], s1);
    }

    // ---- causal mask (diagonal tiles only; padding tiles fully masked)
    if (kv0 + 31 > qr0) {
#pragma unroll
      for (int r = 0; r < 16; ++r)
        if (kv0 + (r & 3) + 8 * (r >> 2) + 4 * hi > qglob) s0[r] = -1e30f;
    }
    if (kv1 + 31 > qr0) {
#pragma unroll
      for (int r = 0; r < 16; ++r)
        if (kv1 + (r & 3) + 8 * (r >> 2) + 4 * hi > qglob) s1[r] = -1e30f;
    }

    // ---- in-register max tree + one cross-half swap
    float m8[8];
#pragma unroll
    for (int r = 0; r < 8; ++r)
      m8[r] = fmaxf(fmaxf(s0[r], s0[r + 8]), fmaxf(s1[r], s1[r + 8]));
    float pm = fmaxf(fmaxf(fmaxf(m8[0], m8[4]), fmaxf(m8[1], m8[5])),
                     fmaxf(fmaxf(m8[2], m8[6]), fmaxf(m8[3], m8[7])));
    pm = xhalf_max(pm);

    if (!__all(pm - mrow <= 8.0f)) {  // defer-max (T13)
      float mn = fmaxf(mrow, pm);
      float sc = exp2f((mrow - mn) * LOG2E);
      lrow *= sc;
#pragma unroll
      for (int r = 0; r < 16; ++r) { o0[r] *= sc; o1[r] *= sc; }
      mrow = mn;
    }

    float p0[16], p1[16];
#pragma unroll
    for (int r = 0; r < 16; ++r) {
      p0[r] = exp2f((s0[r] - mrow) * LOG2E);
      p1[r] = exp2f((s1[r] - mrow) * LOG2E);
    }
    float a8[8];
#pragma unroll
    for (int r = 0; r < 8; ++r) a8[r] = (p0[r] + p0[r + 8]) + (p1[r] + p1[r + 8]);
    float s4 = ((a8[0] + a8[4]) + (a8[1] + a8[5])) + ((a8[2] + a8[6]) + (a8[3] + a8[7]));
    lrow += xhalf_sum(s4);

    // ---- P -> bf16 B-frags via cvt_pk + permlane32_swap (T12).
    // swap(c0,c2) -> (u0, u2); swap(c1,c3) -> (u1, u3)  [chunk kv 0..15]
    // swap(c4,c6) -> (u0, u2); swap(c5,c7) -> (u1, u3)  [chunk kv 16..31]
#define MAKE_FRAGS(P, UA, UB)                                                  \
    {                                                                          \
      unsigned c0 = cvt_pk(P[0], P[1]), c1 = cvt_pk(P[2], P[3]);               \
      unsigned c2 = cvt_pk(P[4], P[5]), c3 = cvt_pk(P[6], P[7]);               \
      unsigned c4 = cvt_pk(P[8], P[9]), c5 = cvt_pk(P[10], P[11]);             \
      unsigned c6 = cvt_pk(P[12], P[13]), c7 = cvt_pk(P[14], P[15]);           \
      uint2v rA = __builtin_amdgcn_permlane32_swap(c0, c2, false, false);      \
      uint2v rB = __builtin_amdgcn_permlane32_swap(c1, c3, false, false);      \
      uint2v rC = __builtin_amdgcn_permlane32_swap(c4, c6, false, false);      \
      uint2v rD = __builtin_amdgcn_permlane32_swap(c5, c7, false, false);      \
      UA.u[0] = rA[0]; UA.u[2] = rA[1];                                        \
      UA.u[1] = rB[0]; UA.u[3] = rB[1];                                        \
      UB.u[0] = rC[0]; UB.u[2] = rC[1];                                        \
      UB.u[1] = rD[0]; UB.u[3] = rD[1];                                        \
    }
    U8 pa00, pa01, pa10, pa11;
    MAKE_FRAGS(p0, pa00, pa01)
    MAKE_FRAGS(p1, pa10, pa11)
#undef MAKE_FRAGS

    // ---- O^T += V^T P^T
    o0 = MFMA32(va[0], pa00.v, o0);
    o0 = MFMA32(va[1], pa01.v, o0);
    o0 = MFMA32(va[2], pa10.v, o0);
    o0 = MFMA32(va[3], pa11.v, o0);
    o1 = MFMA32(va[4], pa00.v, o1);
    o1 = MFMA32(va[5], pa01.v, o1);
    o1 = MFMA32(va[6], pa10.v, o1);
    o1 = MFMA32(va[7], pa11.v, o1);
  }

  // ---- store partials: Op[pid][hd 64][q 32] bf16 (coalesced), m/l per q
  const int pid = b * 576 + u;
  short* Ob = Op + (size_t)pid * 2048;
#pragma unroll
  for (int r = 0; r < 16; ++r) {
    int hd = (r & 3) + 8 * (r >> 2) + 4 * hi;
    Ob[hd * 32 + l31] = f2bf(o0[r]);
    Ob[(32 + hd) * 32 + l31] = f2bf(o1[r]);
  }
  if (hi == 0) {
    mp[pid * 32 + l31] = mrow;
    lp[pid * 32 + l31] = lrow;
  }
}

// ---------------- combine <=8 segment partials per (b,g); LDS transpose out
__global__ __launch_bounds__(256) void attn_combine(const short* __restrict__ Op,
                                                    const float* __restrict__ mp,
                                                    const float* __restrict__ lp,
                                                    float* __restrict__ out) {
  __shared__ float ls[64][33];
  const int g = blockIdx.x;  // 0..127
  const int b = blockIdx.y;  // 0..3
  const int j = g >> 4;
  const int nseg = j + 1;
  const int base = b * 576 + 8 * j * (j + 1) + (g - (j << 4)) * (j + 1);
  const int qc = threadIdx.x & 31, hg = threadIdx.x >> 5;  // hg 0..7

  float mm = -1e30f;
  for (int s2 = 0; s2 < nseg; ++s2) mm = fmaxf(mm, mp[(base + s2) * 32 + qc]);
  float lsum = 0.f;
  float osum[8];
#pragma unroll
  for (int it = 0; it < 8; ++it) osum[it] = 0.f;
  for (int s2 = 0; s2 < nseg; ++s2) {
    float w = exp2f((mp[(base + s2) * 32 + qc] - mm) * LOG2E);
    lsum += lp[(base + s2) * 32 + qc] * w;
    const short* Ob = Op + (size_t)(base + s2) * 2048;
#pragma unroll
    for (int it = 0; it < 8; ++it)
      osum[it] += bf2f(Ob[(hg * 8 + it) * 32 + qc]) * w;
  }
  float inv = 1.0f / lsum;
#pragma unroll
  for (int it = 0; it < 8; ++it) ls[hg * 8 + it][qc] = osum[it] * inv;
  __syncthreads();
  const int lane = threadIdx.x & 63, qq = threadIdx.x >> 6;
#pragma unroll
  for (int p = 0; p < 8; ++p) {
    int qrow = qq * 8 + p;
    out[((size_t)b * 4096 + (size_t)g * 32 + qrow) * 64 + lane] = ls[lane][qrow];
  }
}

extern "C" void kernel_launch(void* const* d_in, const int* in_sizes, int n_in,
                              void* d_out, int out_size, void* d_ws, size_t ws_size,
                              hipStream_t stream) {
  const float* x = (const float*)d_in[0];
  const float* Wq = (const float*)d_in[1];
  const float* Wk = (const float*)d_in[2];
  const float* Wv = (const float*)d_in[3];
  float* out = (float*)d_out;

  char* w = (char*)d_ws;
  short* qb = (short*)(w);                                       // 2 MiB
  short* kb = (short*)(w + (size_t)2 * 1024 * 1024);             // 2 MiB
  short* vT = (short*)(w + (size_t)4 * 1024 * 1024);             // 2 MiB
  short* Wt = (short*)(w + (size_t)6 * 1024 * 1024);             // 384 KiB
  float* mp = (float*)(w + (size_t)6656 * 1024);                 // 288 KiB
  float* lp = (float*)(w + (size_t)7040 * 1024);                 // 288 KiB
  short* Op = (short*)(w + (size_t)7424 * 1024);                 // 9.4 MiB bf16

  prep_w<<<48, 256, 0, stream>>>(Wq, Wk, Wv, Wt);
  qkv_kernel<<<256, 256, 0, stream>>>(x, Wt, qb, kb, vT);
  attn_partial<<<2304, 64, 0, stream>>>(qb, kb, vT, Op, mp, lp);
  attn_combine<<<dim3(128, 4), 256, 0, stream>>>(Op, mp, lp, out);
}

// Round 8
// 110.490 us; speedup vs baseline: 2.5028x; 1.0660x over previous
//
#include <hip/hip_runtime.h>
#include <hip/hip_bf16.h>
#include <math.h>

typedef __attribute__((ext_vector_type(8))) short bf16x8;
typedef __attribute__((ext_vector_type(4))) float f32x4;
typedef __attribute__((ext_vector_type(16))) float f32x16;
typedef __attribute__((ext_vector_type(2))) unsigned uint2v;

#define MFMA16(A, B, C) __builtin_amdgcn_mfma_f32_16x16x32_bf16(A, B, C, 0, 0, 0)
#define MFMA32(A, B, C) __builtin_amdgcn_mfma_f32_32x32x16_bf16(A, B, C, 0, 0, 0)
#define LOG2E 1.44269504f

__device__ __forceinline__ short f2bf(float f) {
  union { __hip_bfloat16 b; short s; } v;
  v.b = __float2bfloat16(f);
  return v.s;
}

__device__ __forceinline__ float bf2f(short s) {
  union { unsigned u; float f; } v;
  v.u = ((unsigned)(unsigned short)s) << 16;
  return v.f;
}

__device__ __forceinline__ bf16x8 cvt8(float4 a, float4 b) {
  bf16x8 r;
  r[0] = f2bf(a.x); r[1] = f2bf(a.y); r[2] = f2bf(a.z); r[3] = f2bf(a.w);
  r[4] = f2bf(b.x); r[5] = f2bf(b.y); r[6] = f2bf(b.z); r[7] = f2bf(b.w);
  return r;
}

__device__ __forceinline__ unsigned cvt_pk(float lo, float hi) {
  unsigned r;
  asm("v_cvt_pk_bf16_f32 %0, %1, %2" : "=v"(r) : "v"(lo), "v"(hi));
  return r;
}

__device__ __forceinline__ void glds16(const void* g, void* l) {
  __builtin_amdgcn_global_load_lds(
      (const __attribute__((address_space(1))) unsigned int*)g,
      (__attribute__((address_space(3))) unsigned int*)l, 16, 0, 0);
}

// permlane32_swap(a,b) -> {a.lo||b.lo, a.hi||b.hi}
__device__ __forceinline__ float xhalf_max(float x) {
  uint2v r = __builtin_amdgcn_permlane32_swap(__float_as_uint(x), __float_as_uint(x),
                                              false, false);
  return fmaxf(__uint_as_float(r[0]), __uint_as_float(r[1]));
}
__device__ __forceinline__ float xhalf_sum(float x) {
  uint2v r = __builtin_amdgcn_permlane32_swap(__float_as_uint(x), __float_as_uint(x),
                                              false, false);
  return __uint_as_float(r[0]) + __uint_as_float(r[1]);
}

// ---------------- weight transpose via LDS tiles: Wt[n][d] bf16, n in [0,192)
__global__ __launch_bounds__(256) void prep_w(const float* __restrict__ Wq,
                                              const float* __restrict__ Wk,
                                              const float* __restrict__ Wv,
                                              short* __restrict__ Wt) {
  __shared__ float ls[64][65];
  const int wsel = blockIdx.x >> 4;
  const int dt = blockIdx.x & 15;
  const float* W = (wsel == 0) ? Wq : ((wsel == 1) ? Wk : Wv);
  const float scale = (wsel == 0) ? 0.03125f : 1.0f;
  const int d0 = dt * 64;
  const int rr = threadIdx.x >> 4;
  const int cc = threadIdx.x & 15;
#pragma unroll
  for (int p = 0; p < 4; ++p) {
    int d = rr + p * 16;
    float4 v = *(const float4*)(W + (size_t)(d0 + d) * 64 + cc * 4);
    ls[d][cc * 4 + 0] = v.x; ls[d][cc * 4 + 1] = v.y;
    ls[d][cc * 4 + 2] = v.z; ls[d][cc * 4 + 3] = v.w;
  }
  __syncthreads();
#pragma unroll
  for (int p = 0; p < 4; ++p) {
    int h = rr + p * 16;
    short4 o;
    o.x = f2bf(ls[cc * 4 + 0][h] * scale);
    o.y = f2bf(ls[cc * 4 + 1][h] * scale);
    o.z = f2bf(ls[cc * 4 + 2][h] * scale);
    o.w = f2bf(ls[cc * 4 + 3][h] * scale);
    *(short4*)(Wt + (size_t)(wsel * 64 + h) * 1024 + d0 + cc * 4) = o;
  }
}

// ---------------- fused QKV v5: 256 blocks x 8 waves, split-K in-block.
// Wave (wm=w&3, kh=w>>2): rows m0+wm*16, K-half kh*512, all 12 nt.
// Barrier-free main loop: per-wave private x staging via global_load_lds
// (8x1KB calls, k-sliced chunk layout -> bank-even ds_reads), double-buffered,
// explicit vmcnt(8)+sched_barrier. Cross-half fp32 reduce through LDS at end.
__global__ __launch_bounds__(512, 2) void qkv_kernel(const float* __restrict__ x,
                                                     const short* __restrict__ Wt,
                                                     short* __restrict__ qo,
                                                     short* __restrict__ ko,
                                                     short* __restrict__ vT) {
  __shared__ __align__(16) char pool[131072];  // 8 waves x dbuf x 8KB
  const int tid = threadIdx.x;
  const int wave = tid >> 6, lane = tid & 63;
  const int lr = lane & 15, lq = lane >> 4;
  const int wm = wave & 3, kh = wave >> 2;
  const int m0 = blockIdx.x * 64;

  char* wbuf = pool + wave * 16384;
  // staging: call j writes 1KB; lane -> (row=lane&15, kq=lane>>4);
  // LDS [chunk j][kq][row] (16B units); global: row-major x
  const float* xsrc = x + (size_t)(m0 + wm * 16 + lr) * 1024 + kh * 512 + lq * 4;

  f32x4 acc[12];
#pragma unroll
  for (int i = 0; i < 12; ++i) acc[i] = f32x4{0.f, 0.f, 0.f, 0.f};

  const short* wtb = Wt + (size_t)lr * 1024 + kh * 512 + lq * 8;

#pragma unroll
  for (int j = 0; j < 8; ++j)  // prologue: stage step 0 -> buf0
    glds16(xsrc + j * 16, wbuf + j * 1024);

#pragma unroll
  for (int s = 0; s < 4; ++s) {
    char* cur = wbuf + (s & 1) * 8192;
    __builtin_amdgcn_sched_barrier(0);
    if (s < 3) {
      char* nxt = wbuf + ((s + 1) & 1) * 8192;
#pragma unroll
      for (int j = 0; j < 8; ++j)
        glds16(xsrc + (s + 1) * 128 + j * 16, nxt + j * 1024);
      __builtin_amdgcn_sched_barrier(0);
      asm volatile("s_waitcnt vmcnt(8)" ::: "memory");  // cur done, 8 in flight
    } else {
      asm volatile("s_waitcnt vmcnt(0)" ::: "memory");
    }
    __builtin_amdgcn_sched_barrier(0);
#pragma unroll
    for (int kc = 0; kc < 4; ++kc) {
      // A-frag floats kc*32+lq*8..+7: chunk kc*2+(lq>>1), kq (lq&1)*2 & +1
      const char* ab = cur + (kc * 2 + (lq >> 1)) * 1024 + (lq & 1) * 512 + lr * 16;
      float4 a0 = *(const float4*)ab;
      float4 a1 = *(const float4*)(ab + 256);
      bf16x8 af = cvt8(a0, a1);
#pragma unroll
      for (int nt = 0; nt < 12; ++nt) {
        bf16x8 bfg = *(const bf16x8*)(wtb + nt * 16384 + s * 128 + kc * 32);
        acc[nt] = MFMA16(af, bfg, acc[nt]);
      }
    }
  }

  // ---- cross-half reduce (reuse pool; fp32 exact)
  __syncthreads();
  f32x4* exch = (f32x4*)pool;
  if (kh == 1) {
#pragma unroll
    for (int nt = 0; nt < 12; ++nt)
      exch[(wm * 12 + nt) * 64 + lane] = acc[nt];
  }
  __syncthreads();
  if (kh == 0) {
#pragma unroll
    for (int nt = 0; nt < 12; ++nt) {
      f32x4 o = exch[(wm * 12 + nt) * 64 + lane];
#pragma unroll
      for (int r = 0; r < 4; ++r) acc[nt][r] += o[r];
    }
#pragma unroll
    for (int nt = 0; nt < 12; ++nt) {
#pragma unroll
      for (int r = 0; r < 4; ++r) {
        int m = m0 + wm * 16 + lq * 4 + r;  // C/D: row=(lane>>4)*4+reg
        int n = nt * 16 + lr;               //      col=lane&15
        short hval = f2bf(acc[nt][r]);
        if (nt < 4) qo[m * 64 + n] = hval;
        else if (nt < 8) ko[m * 64 + (n - 64)] = hval;
        else vT[((m >> 12) << 18) + ((n - 128) << 12) + (m & 4095)] = hval;
      }
    }
  }
}

// ---------------- split-K causal flash, swapped-QK^T 32x32, LDS-free.
// Units: (b, 32-row group g 0..127, 512-wide segment s), 576/batch, 2304 blocks.
__global__ __launch_bounds__(64, 2) void attn_partial(const short* __restrict__ qbuf,
                                                      const short* __restrict__ kbuf,
                                                      const short* __restrict__ vbuf,
                                                      short* __restrict__ Op,
                                                      float* __restrict__ mp,
                                                      float* __restrict__ lp) {
  const int id = blockIdx.x;
  const int b = (id & 7) >> 1;                 // 2 XCDs per batch
  const int u = ((id >> 3) << 1) | (id & 1);   // 0..575
  int j = 0;
  while (u >= 8 * (j + 1) * (j + 2)) ++j;      // tier: nseg = j+1
  const int t = u - 8 * j * (j + 1);
  const int gl = t / (j + 1);
  const int s = t - gl * (j + 1);
  const int g = (j << 4) + gl;
  const int qr0 = g << 5;
  const int kv_lo = s << 9;
  const int kv_hi = (s == j) ? (qr0 + 32) : ((s + 1) << 9);

  const int lane = threadIdx.x;
  const int l31 = lane & 31, hi = lane >> 5;
  const int qglob = qr0 + l31;

  const short* qb = qbuf + ((size_t)b << 18);
  const short* kb = kbuf + ((size_t)b << 18);
  const short* vb = vbuf + ((size_t)b << 18);

  bf16x8 bq[4];
#pragma unroll
  for (int c = 0; c < 4; ++c)
    bq[c] = *(const bf16x8*)(qb + (size_t)(qr0 + l31) * 64 + c * 16 + hi * 8);

  f32x16 o0, o1;
#pragma unroll
  for (int r = 0; r < 16; ++r) { o0[r] = 0.f; o1[r] = 0.f; }
  float mrow = -1e30f, lrow = 0.f;

  union U8 { unsigned u[4]; bf16x8 v; };

  for (int kv0 = kv_lo; kv0 < kv_hi; kv0 += 64) {
    const int kv1 = kv0 + 32;
    bf16x8 ka[4], kc[4], va[8];
#pragma unroll
    for (int c = 0; c < 4; ++c) {
      ka[c] = *(const bf16x8*)(kb + (size_t)(kv0 + l31) * 64 + c * 16 + hi * 8);
      kc[c] = *(const bf16x8*)(kb + (size_t)(kv1 + l31) * 64 + c * 16 + hi * 8);
    }
#pragma unroll
    for (int h = 0; h < 2; ++h) {
      const short* vrow = vb + (size_t)(32 * h + l31) * 4096;
      va[h * 4 + 0] = *(const bf16x8*)(vrow + kv0 + hi * 8);
      va[h * 4 + 1] = *(const bf16x8*)(vrow + kv0 + 16 + hi * 8);
      va[h * 4 + 2] = *(const bf16x8*)(vrow + kv1 + hi * 8);
      va[h * 4 + 3] = *(const bf16x8*)(vrow + kv1 + 16 + hi * 8);
    }

    f32x16 s0, s1;
#pragma unroll
    for (int r = 0; r < 16; ++r) { s0[r] = 0.f; s1[r] = 0.f; }
#pragma unroll
    for (int c = 0; c < 4; ++c) {
      s0 = MFMA32(ka[c], bq[c], s0);
      s1 = MFMA32(kc[c], bq[c], s1);
    }

    if (kv0 + 31 > qr0) {
#pragma unroll
      for (int r = 0; r < 16; ++r)
        if (kv0 + (r & 3) + 8 * (r >> 2) + 4 * hi > qglob) s0[r] = -1e30f;
    }
    if (kv1 + 31 > qr0) {
#pragma unroll
      for (int r = 0; r < 16; ++r)
        if (kv1 + (r & 3) + 8 * (r >> 2) + 4 * hi > qglob) s1[r] = -1e30f;
    }

    float m8[8];
#pragma unroll
    for (int r = 0; r < 8; ++r)
      m8[r] = fmaxf(fmaxf(s0[r], s0[r + 8]), fmaxf(s1[r], s1[r + 8]));
    float pm = fmaxf(fmaxf(fmaxf(m8[0], m8[4]), fmaxf(m8[1], m8[5])),
                     fmaxf(fmaxf(m8[2], m8[6]), fmaxf(m8[3], m8[7])));
    pm = xhalf_max(pm);

    if (!__all(pm - mrow <= 8.0f)) {  // defer-max (T13)
      float mn = fmaxf(mrow, pm);
      float sc = exp2f((mrow - mn) * LOG2E);
      lrow *= sc;
#pragma unroll
      for (int r = 0; r < 16; ++r) { o0[r] *= sc; o1[r] *= sc; }
      mrow = mn;
    }

    float p0[16], p1[16];
#pragma unroll
    for (int r = 0; r < 16; ++r) {
      p0[r] = exp2f((s0[r] - mrow) * LOG2E);
      p1[r] = exp2f((s1[r] - mrow) * LOG2E);
    }
    float a8[8];
#pragma unroll
    for (int r = 0; r < 8; ++r) a8[r] = (p0[r] + p0[r + 8]) + (p1[r] + p1[r + 8]);
    float s4 = ((a8[0] + a8[4]) + (a8[1] + a8[5])) + ((a8[2] + a8[6]) + (a8[3] + a8[7]));
    lrow += xhalf_sum(s4);

    // P -> bf16 B-frags via cvt_pk + permlane32_swap (T12)
#define MAKE_FRAGS(P, UA, UB)                                                  \
    {                                                                          \
      unsigned c0 = cvt_pk(P[0], P[1]), c1 = cvt_pk(P[2], P[3]);               \
      unsigned c2 = cvt_pk(P[4], P[5]), c3 = cvt_pk(P[6], P[7]);               \
      unsigned c4 = cvt_pk(P[8], P[9]), c5 = cvt_pk(P[10], P[11]);             \
      unsigned c6 = cvt_pk(P[12], P[13]), c7 = cvt_pk(P[14], P[15]);           \
      uint2v rA = __builtin_amdgcn_permlane32_swap(c0, c2, false, false);      \
      uint2v rB = __builtin_amdgcn_permlane32_swap(c1, c3, false, false);      \
      uint2v rC = __builtin_amdgcn_permlane32_swap(c4, c6, false, false);      \
      uint2v rD = __builtin_amdgcn_permlane32_swap(c5, c7, false, false);      \
      UA.u[0] = rA[0]; UA.u[2] = rA[1];                                        \
      UA.u[1] = rB[0]; UA.u[3] = rB[1];                                        \
      UB.u[0] = rC[0]; UB.u[2] = rC[1];                                        \
      UB.u[1] = rD[0]; UB.u[3] = rD[1];                                        \
    }
    U8 pa00, pa01, pa10, pa11;
    MAKE_FRAGS(p0, pa00, pa01)
    MAKE_FRAGS(p1, pa10, pa11)
#undef MAKE_FRAGS

    o0 = MFMA32(va[0], pa00.v, o0);
    o0 = MFMA32(va[1], pa01.v, o0);
    o0 = MFMA32(va[2], pa10.v, o0);
    o0 = MFMA32(va[3], pa11.v, o0);
    o1 = MFMA32(va[4], pa00.v, o1);
    o1 = MFMA32(va[5], pa01.v, o1);
    o1 = MFMA32(va[6], pa10.v, o1);
    o1 = MFMA32(va[7], pa11.v, o1);
  }

  const int pid = b * 576 + u;
  short* Ob = Op + (size_t)pid * 2048;
#pragma unroll
  for (int r = 0; r < 16; ++r) {
    int hd = (r & 3) + 8 * (r >> 2) + 4 * hi;
    Ob[hd * 32 + l31] = f2bf(o0[r]);
    Ob[(32 + hd) * 32 + l31] = f2bf(o1[r]);
  }
  if (hi == 0) {
    mp[pid * 32 + l31] = mrow;
    lp[pid * 32 + l31] = lrow;
  }
}

// ---------------- combine <=8 segment partials per (b,g); LDS transpose out
__global__ __launch_bounds__(256) void attn_combine(const short* __restrict__ Op,
                                                    const float* __restrict__ mp,
                                                    const float* __restrict__ lp,
                                                    float* __restrict__ out) {
  __shared__ float ls[64][33];
  const int g = blockIdx.x;  // 0..127
  const int b = blockIdx.y;  // 0..3
  const int j = g >> 4;
  const int nseg = j + 1;
  const int base = b * 576 + 8 * j * (j + 1) + (g - (j << 4)) * (j + 1);
  const int qc = threadIdx.x & 31, hg = threadIdx.x >> 5;  // hg 0..7

  float mm = -1e30f;
  for (int s2 = 0; s2 < nseg; ++s2) mm = fmaxf(mm, mp[(base + s2) * 32 + qc]);
  float lsum = 0.f;
  float osum[8];
#pragma unroll
  for (int it = 0; it < 8; ++it) osum[it] = 0.f;
  for (int s2 = 0; s2 < nseg; ++s2) {
    float w = exp2f((mp[(base + s2) * 32 + qc] - mm) * LOG2E);
    lsum += lp[(base + s2) * 32 + qc] * w;
    const short* Ob = Op + (size_t)(base + s2) * 2048;
#pragma unroll
    for (int it = 0; it < 8; ++it)
      osum[it] += bf2f(Ob[(hg * 8 + it) * 32 + qc]) * w;
  }
  float inv = 1.0f / lsum;
#pragma unroll
  for (int it = 0; it < 8; ++it) ls[hg * 8 + it][qc] = osum[it] * inv;
  __syncthreads();
  const int lane = threadIdx.x & 63, qq = threadIdx.x >> 6;
#pragma unroll
  for (int p = 0; p < 8; ++p) {
    int qrow = qq * 8 + p;
    out[((size_t)b * 4096 + (size_t)g * 32 + qrow) * 64 + lane] = ls[lane][qrow];
  }
}

extern "C" void kernel_launch(void* const* d_in, const int* in_sizes, int n_in,
                              void* d_out, int out_size, void* d_ws, size_t ws_size,
                              hipStream_t stream) {
  const float* x = (const float*)d_in[0];
  const float* Wq = (const float*)d_in[1];
  const float* Wk = (const float*)d_in[2];
  const float* Wv = (const float*)d_in[3];
  float* out = (float*)d_out;

  char* w = (char*)d_ws;
  short* qb = (short*)(w);                                       // 2 MiB
  short* kb = (short*)(w + (size_t)2 * 1024 * 1024);             // 2 MiB
  short* vT = (short*)(w + (size_t)4 * 1024 * 1024);             // 2 MiB
  short* Wt = (short*)(w + (size_t)6 * 1024 * 1024);             // 384 KiB
  float* mp = (float*)(w + (size_t)6656 * 1024);                 // 288 KiB
  float* lp = (float*)(w + (size_t)7040 * 1024);                 // 288 KiB
  short* Op = (short*)(w + (size_t)7424 * 1024);                 // 9.4 MiB bf16

  prep_w<<<48, 256, 0, stream>>>(Wq, Wk, Wv, Wt);
  qkv_kernel<<<256, 512, 0, stream>>>(x, Wt, qb, kb, vT);
  attn_partial<<<2304, 64, 0, stream>>>(qb, kb, vT, Op, mp, lp);
  attn_combine<<<dim3(128, 4), 256, 0, stream>>>(Op, mp, lp, out);
}

// Round 9
// 85.409 us; speedup vs baseline: 3.2378x; 1.2937x over previous
//
#include <hip/hip_runtime.h>
#include <hip/hip_bf16.h>
#include <math.h>

typedef __attribute__((ext_vector_type(8))) short bf16x8;
typedef __attribute__((ext_vector_type(4))) float f32x4;
typedef __attribute__((ext_vector_type(16))) float f32x16;
typedef __attribute__((ext_vector_type(2))) unsigned uint2v;

#define MFMA16(A, B, C) __builtin_amdgcn_mfma_f32_16x16x32_bf16(A, B, C, 0, 0, 0)
#define MFMA32(A, B, C) __builtin_amdgcn_mfma_f32_32x32x16_bf16(A, B, C, 0, 0, 0)
#define LOG2E 1.44269504f

__device__ __forceinline__ short f2bf(float f) {
  union { __hip_bfloat16 b; short s; } v;
  v.b = __float2bfloat16(f);
  return v.s;
}

__device__ __forceinline__ float bf2f(short s) {
  union { unsigned u; float f; } v;
  v.u = ((unsigned)(unsigned short)s) << 16;
  return v.f;
}

__device__ __forceinline__ bf16x8 cvt8(float4 a, float4 b) {
  bf16x8 r;
  r[0] = f2bf(a.x); r[1] = f2bf(a.y); r[2] = f2bf(a.z); r[3] = f2bf(a.w);
  r[4] = f2bf(b.x); r[5] = f2bf(b.y); r[6] = f2bf(b.z); r[7] = f2bf(b.w);
  return r;
}

__device__ __forceinline__ unsigned cvt_pk(float lo, float hi) {
  unsigned r;
  asm("v_cvt_pk_bf16_f32 %0, %1, %2" : "=v"(r) : "v"(lo), "v"(hi));
  return r;
}

__device__ __forceinline__ void glds16(const void* g, void* l) {
  __builtin_amdgcn_global_load_lds(
      (const __attribute__((address_space(1))) unsigned int*)g,
      (__attribute__((address_space(3))) unsigned int*)l, 16, 0, 0);
}

// permlane32_swap(a,b) -> {a.lo||b.lo, a.hi||b.hi}
__device__ __forceinline__ float xhalf_max(float x) {
  uint2v r = __builtin_amdgcn_permlane32_swap(__float_as_uint(x), __float_as_uint(x),
                                              false, false);
  return fmaxf(__uint_as_float(r[0]), __uint_as_float(r[1]));
}
__device__ __forceinline__ float xhalf_sum(float x) {
  uint2v r = __builtin_amdgcn_permlane32_swap(__float_as_uint(x), __float_as_uint(x),
                                              false, false);
  return __uint_as_float(r[0]) + __uint_as_float(r[1]);
}

// ---------------- weight transpose via LDS tiles: Wt[n][d] bf16, n in [0,192)
__global__ __launch_bounds__(256) void prep_w(const float* __restrict__ Wq,
                                              const float* __restrict__ Wk,
                                              const float* __restrict__ Wv,
                                              short* __restrict__ Wt) {
  __shared__ float ls[64][65];
  const int wsel = blockIdx.x >> 4;
  const int dt = blockIdx.x & 15;
  const float* W = (wsel == 0) ? Wq : ((wsel == 1) ? Wk : Wv);
  const float scale = (wsel == 0) ? 0.03125f : 1.0f;
  const int d0 = dt * 64;
  const int rr = threadIdx.x >> 4;
  const int cc = threadIdx.x & 15;
#pragma unroll
  for (int p = 0; p < 4; ++p) {
    int d = rr + p * 16;
    float4 v = *(const float4*)(W + (size_t)(d0 + d) * 64 + cc * 4);
    ls[d][cc * 4 + 0] = v.x; ls[d][cc * 4 + 1] = v.y;
    ls[d][cc * 4 + 2] = v.z; ls[d][cc * 4 + 3] = v.w;
  }
  __syncthreads();
#pragma unroll
  for (int p = 0; p < 4; ++p) {
    int h = rr + p * 16;
    short4 o;
    o.x = f2bf(ls[cc * 4 + 0][h] * scale);
    o.y = f2bf(ls[cc * 4 + 1][h] * scale);
    o.z = f2bf(ls[cc * 4 + 2][h] * scale);
    o.w = f2bf(ls[cc * 4 + 3][h] * scale);
    *(short4*)(Wt + (size_t)(wsel * 64 + h) * 1024 + d0 + cc * 4) = o;
  }
}

// ---------------- fused QKV v6: m97/T3 2-phase template.
// 256 blocks x 512 thr (8 waves). BM=64, N=192 full, BK=64, 16 K-steps.
// Both operands glds-staged to LDS (pre-swizzled global src), double-buffered
// (2x40KB), ONE barrier/step, no inline asm (compiler schedules waitcnts).
// Wave (wm=w&1, wn=w>>1): rows wm*32..+31, nt wn*3..+2. Coalesced epilogue.
__global__ __launch_bounds__(512, 4) void qkv_kernel(const float* __restrict__ x,
                                                     const short* __restrict__ Wt,
                                                     short* __restrict__ qo,
                                                     short* __restrict__ ko,
                                                     short* __restrict__ vT) {
  __shared__ __align__(16) char pool[81920];  // 2 x (16KB x-tile + 24KB Wt-tile)
  const int tid = threadIdx.x;
  const int wave = tid >> 6, lane = tid & 63;
  const int lr = lane & 15, lq = lane >> 4;
  const int wm = wave & 1, wn = wave >> 1;
  const int m0 = blockIdx.x * 64;

  f32x4 acc[2][3];
#pragma unroll
  for (int mi = 0; mi < 2; ++mi)
#pragma unroll
    for (int j = 0; j < 3; ++j) acc[mi][j] = f32x4{0.f, 0.f, 0.f, 0.f};

  // --- staging source pointers (t-independent), pre-swizzled (rule #21)
  // x: round r covers rows wave*4+(lane>>4)+r*32; col16=lane&15 (16B units)
  //    LDS logical [row][256B]: float at col16*4 comes from global
  //    gcol = ((col16>>1)^(row&7))*8 + (col16&1)*4
  const int xrow0 = wave * 4 + (lane >> 4);
  const int col16 = lane & 15;
  const float* xg[2];
#pragma unroll
  for (int r = 0; r < 2; ++r) {
    int srow = xrow0 + r * 32;
    xg[r] = x + (size_t)(m0 + srow) * 1024 +
            (((col16 >> 1) ^ (srow & 7)) << 3) + ((col16 & 1) << 2);
  }
  // Wt: round r covers n = wave*8+(lane>>3)+r*64; col8=lane&7 (16B units)
  //     gk = (col8^(n&7))*8 bf16
  const int wrow0 = wave * 8 + (lane >> 3);
  const int col8 = lane & 7;
  const short* wg[3];
#pragma unroll
  for (int r = 0; r < 3; ++r) {
    int n = wrow0 + r * 64;
    wg[r] = Wt + (size_t)n * 1024 + ((col8 ^ (n & 7)) << 3);
  }
  const int dst_off = wave * 1024;  // wave-uniform; lane adds lane*16 in HW

#define STAGE(c, t)                                                         \
  {                                                                         \
    char* xb_ = pool + (c) * 40960;                                         \
    _Pragma("unroll") for (int r = 0; r < 2; ++r)                           \
        glds16(xg[r] + (t) * 64, xb_ + r * 8192 + dst_off);                 \
    _Pragma("unroll") for (int r = 0; r < 3; ++r)                           \
        glds16(wg[r] + (t) * 64, xb_ + 16384 + r * 8192 + dst_off);         \
  }

  STAGE(0, 0)
  __syncthreads();  // compiler emits vmcnt(0) before barrier -> tile 0 ready

  int cur = 0;
  for (int t = 0; t < 16; ++t) {
    if (t < 15) STAGE(cur ^ 1, t + 1)  // prefetch into other buffer
    const char* xb = pool + cur * 40960;
    const char* wb = xb + 16384;
#pragma unroll
    for (int kc = 0; kc < 2; ++kc) {
      bf16x8 bfg[3];
#pragma unroll
      for (int j = 0; j < 3; ++j) {
        int n = (wn * 3 + j) * 16 + lr;
        int unit = kc * 4 + lq;
        bfg[j] = *(const bf16x8*)(wb + n * 128 + ((unit ^ (n & 7)) << 4));
      }
#pragma unroll
      for (int mi = 0; mi < 2; ++mi) {
        int row = wm * 32 + mi * 16 + lr;
        int p = kc * 4 + lq;
        const char* xr = xb + row * 256 + ((p ^ (row & 7)) << 5);
        float4 a0 = *(const float4*)xr;
        float4 a1 = *(const float4*)(xr + 16);
        bf16x8 af = cvt8(a0, a1);
#pragma unroll
        for (int j = 0; j < 3; ++j) acc[mi][j] = MFMA16(af, bfg[j], acc[mi][j]);
      }
    }
    __syncthreads();
    cur ^= 1;
  }
#undef STAGE

  // ---- epilogue: q/k via LDS transpose (b128 stores); vT via short4 stores.
  short* els = (short*)pool;  // [64 m][136 shorts] (272B rows: aligned + bank-spread)
#pragma unroll
  for (int j = 0; j < 3; ++j) {
    int nt = wn * 3 + j;
#pragma unroll
    for (int mi = 0; mi < 2; ++mi) {
      if (nt < 8) {
#pragma unroll
        for (int r = 0; r < 4; ++r) {
          int mloc = wm * 32 + mi * 16 + lq * 4 + r;
          els[mloc * 136 + nt * 16 + lr] = f2bf(acc[mi][j][r]);
        }
      } else {
        int m = m0 + wm * 32 + mi * 16 + lq * 4;  // 4 consecutive m
        short4 h;
        h.x = f2bf(acc[mi][j][0]); h.y = f2bf(acc[mi][j][1]);
        h.z = f2bf(acc[mi][j][2]); h.w = f2bf(acc[mi][j][3]);
        *(short4*)(vT + ((m >> 12) << 18) + ((nt * 16 + lr - 128) << 12) +
                   (m & 4095)) = h;
      }
    }
  }
  __syncthreads();
  {
    const int m = tid >> 3, nq = tid & 7;
    bf16x8 vq = *(const bf16x8*)(els + m * 136 + nq * 8);
    bf16x8 vk = *(const bf16x8*)(els + m * 136 + 64 + nq * 8);
    *(bf16x8*)(qo + (size_t)(m0 + m) * 64 + nq * 8) = vq;
    *(bf16x8*)(ko + (size_t)(m0 + m) * 64 + nq * 8) = vk;
  }
}

// ---------------- split-K causal flash, swapped-QK^T 32x32, LDS-free.
// Units: (b, 32-row group g 0..127, 512-wide segment s), 576/batch, 2304 blocks.
__global__ __launch_bounds__(64, 2) void attn_partial(const short* __restrict__ qbuf,
                                                      const short* __restrict__ kbuf,
                                                      const short* __restrict__ vbuf,
                                                      short* __restrict__ Op,
                                                      float* __restrict__ mp,
                                                      float* __restrict__ lp) {
  const int id = blockIdx.x;
  const int b = (id & 7) >> 1;                 // 2 XCDs per batch
  const int u = ((id >> 3) << 1) | (id & 1);   // 0..575
  int j = 0;
  while (u >= 8 * (j + 1) * (j + 2)) ++j;      // tier: nseg = j+1
  const int t = u - 8 * j * (j + 1);
  const int gl = t / (j + 1);
  const int s = t - gl * (j + 1);
  const int g = (j << 4) + gl;
  const int qr0 = g << 5;
  const int kv_lo = s << 9;
  const int kv_hi = (s == j) ? (qr0 + 32) : ((s + 1) << 9);

  const int lane = threadIdx.x;
  const int l31 = lane & 31, hi = lane >> 5;
  const int qglob = qr0 + l31;

  const short* qb = qbuf + ((size_t)b << 18);
  const short* kb = kbuf + ((size_t)b << 18);
  const short* vb = vbuf + ((size_t)b << 18);

  bf16x8 bq[4];
#pragma unroll
  for (int c = 0; c < 4; ++c)
    bq[c] = *(const bf16x8*)(qb + (size_t)(qr0 + l31) * 64 + c * 16 + hi * 8);

  f32x16 o0, o1;
#pragma unroll
  for (int r = 0; r < 16; ++r) { o0[r] = 0.f; o1[r] = 0.f; }
  float mrow = -1e30f, lrow = 0.f;

  union U8 { unsigned u[4]; bf16x8 v; };

  for (int kv0 = kv_lo; kv0 < kv_hi; kv0 += 64) {
    const int kv1 = kv0 + 32;
    bf16x8 ka[4], kc[4], va[8];
#pragma unroll
    for (int c = 0; c < 4; ++c) {
      ka[c] = *(const bf16x8*)(kb + (size_t)(kv0 + l31) * 64 + c * 16 + hi * 8);
      kc[c] = *(const bf16x8*)(kb + (size_t)(kv1 + l31) * 64 + c * 16 + hi * 8);
    }
#pragma unroll
    for (int h = 0; h < 2; ++h) {
      const short* vrow = vb + (size_t)(32 * h + l31) * 4096;
      va[h * 4 + 0] = *(const bf16x8*)(vrow + kv0 + hi * 8);
      va[h * 4 + 1] = *(const bf16x8*)(vrow + kv0 + 16 + hi * 8);
      va[h * 4 + 2] = *(const bf16x8*)(vrow + kv1 + hi * 8);
      va[h * 4 + 3] = *(const bf16x8*)(vrow + kv1 + 16 + hi * 8);
    }

    f32x16 s0, s1;
#pragma unroll
    for (int r = 0; r < 16; ++r) { s0[r] = 0.f; s1[r] = 0.f; }
#pragma unroll
    for (int c = 0; c < 4; ++c) {
      s0 = MFMA32(ka[c], bq[c], s0);
      s1 = MFMA32(kc[c], bq[c], s1);
    }

    if (kv0 + 31 > qr0) {
#pragma unroll
      for (int r = 0; r < 16; ++r)
        if (kv0 + (r & 3) + 8 * (r >> 2) + 4 * hi > qglob) s0[r] = -1e30f;
    }
    if (kv1 + 31 > qr0) {
#pragma unroll
      for (int r = 0; r < 16; ++r)
        if (kv1 + (r & 3) + 8 * (r >> 2) + 4 * hi > qglob) s1[r] = -1e30f;
    }

    float m8[8];
#pragma unroll
    for (int r = 0; r < 8; ++r)
      m8[r] = fmaxf(fmaxf(s0[r], s0[r + 8]), fmaxf(s1[r], s1[r + 8]));
    float pm = fmaxf(fmaxf(fmaxf(m8[0], m8[4]), fmaxf(m8[1], m8[5])),
                     fmaxf(fmaxf(m8[2], m8[6]), fmaxf(m8[3], m8[7])));
    pm = xhalf_max(pm);

    if (!__all(pm - mrow <= 8.0f)) {  // defer-max (T13)
      float mn = fmaxf(mrow, pm);
      float sc = exp2f((mrow - mn) * LOG2E);
      lrow *= sc;
#pragma unroll
      for (int r = 0; r < 16; ++r) { o0[r] *= sc; o1[r] *= sc; }
      mrow = mn;
    }

    float p0[16], p1[16];
#pragma unroll
    for (int r = 0; r < 16; ++r) {
      p0[r] = exp2f((s0[r] - mrow) * LOG2E);
      p1[r] = exp2f((s1[r] - mrow) * LOG2E);
    }
    float a8[8];
#pragma unroll
    for (int r = 0; r < 8; ++r) a8[r] = (p0[r] + p0[r + 8]) + (p1[r] + p1[r + 8]);
    float s4 = ((a8[0] + a8[4]) + (a8[1] + a8[5])) + ((a8[2] + a8[6]) + (a8[3] + a8[7]));
    lrow += xhalf_sum(s4);

    // P -> bf16 B-frags via cvt_pk + permlane32_swap (T12)
#define MAKE_FRAGS(P, UA, UB)                                                  \
    {                                                                          \
      unsigned c0 = cvt_pk(P[0], P[1]), c1 = cvt_pk(P[2], P[3]);               \
      unsigned c2 = cvt_pk(P[4], P[5]), c3 = cvt_pk(P[6], P[7]);               \
      unsigned c4 = cvt_pk(P[8], P[9]), c5 = cvt_pk(P[10], P[11]);             \
      unsigned c6 = cvt_pk(P[12], P[13]), c7 = cvt_pk(P[14], P[15]);           \
      uint2v rA = __builtin_amdgcn_permlane32_swap(c0, c2, false, false);      \
      uint2v rB = __builtin_amdgcn_permlane32_swap(c1, c3, false, false);      \
      uint2v rC = __builtin_amdgcn_permlane32_swap(c4, c6, false, false);      \
      uint2v rD = __builtin_amdgcn_permlane32_swap(c5, c7, false, false);      \
      UA.u[0] = rA[0]; UA.u[2] = rA[1];                                        \
      UA.u[1] = rB[0]; UA.u[3] = rB[1];                                        \
      UB.u[0] = rC[0]; UB.u[2] = rC[1];                                        \
      UB.u[1] = rD[0]; UB.u[3] = rD[1];                                        \
    }
    U8 pa00, pa01, pa10, pa11;
    MAKE_FRAGS(p0, pa00, pa01)
    MAKE_FRAGS(p1, pa10, pa11)
#undef MAKE_FRAGS

    o0 = MFMA32(va[0], pa00.v, o0);
    o0 = MFMA32(va[1], pa01.v, o0);
    o0 = MFMA32(va[2], pa10.v, o0);
    o0 = MFMA32(va[3], pa11.v, o0);
    o1 = MFMA32(va[4], pa00.v, o1);
    o1 = MFMA32(va[5], pa01.v, o1);
    o1 = MFMA32(va[6], pa10.v, o1);
    o1 = MFMA32(va[7], pa11.v, o1);
  }

  const int pid = b * 576 + u;
  short* Ob = Op + (size_t)pid * 2048;
#pragma unroll
  for (int r = 0; r < 16; ++r) {
    int hd = (r & 3) + 8 * (r >> 2) + 4 * hi;
    Ob[hd * 32 + l31] = f2bf(o0[r]);
    Ob[(32 + hd) * 32 + l31] = f2bf(o1[r]);
  }
  if (hi == 0) {
    mp[pid * 32 + l31] = mrow;
    lp[pid * 32 + l31] = lrow;
  }
}

// ---------------- combine <=8 segment partials per (b,g); LDS transpose out
__global__ __launch_bounds__(256) void attn_combine(const short* __restrict__ Op,
                                                    const float* __restrict__ mp,
                                                    const float* __restrict__ lp,
                                                    float* __restrict__ out) {
  __shared__ float ls[64][33];
  const int g = blockIdx.x;  // 0..127
  const int b = blockIdx.y;  // 0..3
  const int j = g >> 4;
  const int nseg = j + 1;
  const int base = b * 576 + 8 * j * (j + 1) + (g - (j << 4)) * (j + 1);
  const int qc = threadIdx.x & 31, hg = threadIdx.x >> 5;  // hg 0..7

  float mm = -1e30f;
  for (int s2 = 0; s2 < nseg; ++s2) mm = fmaxf(mm, mp[(base + s2) * 32 + qc]);
  float lsum = 0.f;
  float osum[8];
#pragma unroll
  for (int it = 0; it < 8; ++it) osum[it] = 0.f;
  for (int s2 = 0; s2 < nseg; ++s2) {
    float w = exp2f((mp[(base + s2) * 32 + qc] - mm) * LOG2E);
    lsum += lp[(base + s2) * 32 + qc] * w;
    const short* Ob = Op + (size_t)(base + s2) * 2048;
#pragma unroll
    for (int it = 0; it < 8; ++it)
      osum[it] += bf2f(Ob[(hg * 8 + it) * 32 + qc]) * w;
  }
  float inv = 1.0f / lsum;
#pragma unroll
  for (int it = 0; it < 8; ++it) ls[hg * 8 + it][qc] = osum[it] * inv;
  __syncthreads();
  const int lane = threadIdx.x & 63, qq = threadIdx.x >> 6;
#pragma unroll
  for (int p = 0; p < 8; ++p) {
    int qrow = qq * 8 + p;
    out[((size_t)b * 4096 + (size_t)g * 32 + qrow) * 64 + lane] = ls[lane][qrow];
  }
}

extern "C" void kernel_launch(void* const* d_in, const int* in_sizes, int n_in,
                              void* d_out, int out_size, void* d_ws, size_t ws_size,
                              hipStream_t stream) {
  const float* x = (const float*)d_in[0];
  const float* Wq = (const float*)d_in[1];
  const float* Wk = (const float*)d_in[2];
  const float* Wv = (const float*)d_in[3];
  float* out = (float*)d_out;

  char* w = (char*)d_ws;
  short* qb = (short*)(w);                                       // 2 MiB
  short* kb = (short*)(w + (size_t)2 * 1024 * 1024);             // 2 MiB
  short* vT = (short*)(w + (size_t)4 * 1024 * 1024);             // 2 MiB
  short* Wt = (short*)(w + (size_t)6 * 1024 * 1024);             // 384 KiB
  float* mp = (float*)(w + (size_t)6656 * 1024);                 // 288 KiB
  float* lp = (float*)(w + (size_t)7040 * 1024);                 // 288 KiB
  short* Op = (short*)(w + (size_t)7424 * 1024);                 // 9.4 MiB bf16

  prep_w<<<48, 256, 0, stream>>>(Wq, Wk, Wv, Wt);
  qkv_kernel<<<256, 512, 0, stream>>>(x, Wt, qb, kb, vT);
  attn_partial<<<2304, 64, 0, stream>>>(qb, kb, vT, Op, mp, lp);
  attn_combine<<<dim3(128, 4), 256, 0, stream>>>(Op, mp, lp, out);
}